// Round 10
// baseline (1834.045 us; speedup 1.0000x reference)
//
#include <hip/hip_runtime.h>
#include <hip/hip_bf16.h>
#include <math.h>

#define Bz 2
#define Tz 2048
#define Dz 1024
#define Hz 16
#define DHz 64
#define BNz 1024
#define TOPKz 64
#define QBLK 16
#define CAND_MAX 224
#define KEEP_MAX 96
#define DELTA 0.35f   // >= 2x bf16-screen error bound (validated r6-r9)
#define BAND 8e-5f    // ambiguity half-band on RAW scores (verified r5-r9)
#define CNT_HI 128    // bisection window upper bound (window [64,128])
#define BIS_ITERS 24

typedef __attribute__((ext_vector_type(8))) short bf16x8;
typedef __attribute__((ext_vector_type(4))) float f32x4;

__device__ __forceinline__ short f2bf(float f) {     // RNE f32 -> bf16
  unsigned u = __float_as_uint(f);
  return (short)((u + 0x7FFFu + ((u >> 16) & 1u)) >> 16);
}

// ---- QK GEMM in f64: columns [0, 2048). Writes q64, k64 (t-major) and
//      kbf (bf16 K panel, t-major, for the MFMA screen). -------------------
__global__ __launch_bounds__(256) void qk_gemm_f64(
    const float* __restrict__ A, const float* __restrict__ W,
    const float* __restrict__ bias,
    double* __restrict__ q64, double* __restrict__ k64, short* __restrict__ kbf)
{
  __shared__ __align__(32) double As[16][68];
  __shared__ __align__(32) double Ws[16][68];
  const int tid = threadIdx.x;
  const int tx = tid & 15, ty = tid >> 4;
  const int m0 = blockIdx.y * 64, n0 = blockIdx.x * 64;
  const int lrow = tid >> 2, lkq = tid & 3;
  double acc[4][4] = {};
  const float* Aload = A + (size_t)(m0 + lrow) * Dz + lkq * 4;
  const float* Wload = W + (size_t)(n0 + lrow) * Dz + lkq * 4;
  for (int kt = 0; kt < Dz; kt += 16) {
    float4 a4 = *(const float4*)(Aload + kt);
    float4 w4 = *(const float4*)(Wload + kt);
    __syncthreads();
    As[lkq*4+0][lrow] = (double)a4.x; As[lkq*4+1][lrow] = (double)a4.y;
    As[lkq*4+2][lrow] = (double)a4.z; As[lkq*4+3][lrow] = (double)a4.w;
    Ws[lkq*4+0][lrow] = (double)w4.x; Ws[lkq*4+1][lrow] = (double)w4.y;
    Ws[lkq*4+2][lrow] = (double)w4.z; Ws[lkq*4+3][lrow] = (double)w4.w;
    __syncthreads();
#pragma unroll
    for (int k = 0; k < 16; ++k) {
      double4 av = *(const double4*)&As[k][ty*4];
      double4 wv = *(const double4*)&Ws[k][tx*4];
      double a_[4] = {av.x, av.y, av.z, av.w};
      double w_[4] = {wv.x, wv.y, wv.z, wv.w};
#pragma unroll
      for (int i = 0; i < 4; ++i)
#pragma unroll
        for (int j = 0; j < 4; ++j)
          acc[i][j] = fma(a_[i], w_[j], acc[i][j]);
    }
  }
#pragma unroll
  for (int i = 0; i < 4; ++i) {
    int m = m0 + ty*4 + i;
    int bb = m / Tz, t = m % Tz;
#pragma unroll
    for (int j = 0; j < 4; ++j) {
      int n = n0 + tx*4 + j;
      double val = acc[i][j] + (double)bias[n];
      if (n < BNz) {
        int h = n >> 6, d = n & 63;
        q64[(((size_t)(bb*Hz + h))*Tz + t)*DHz + d] = val;
      } else {
        int h = (n - BNz) >> 6, d = n & 63;
        size_t bh = (size_t)(bb*Hz + h);
        k64[(bh*Tz + t)*DHz + d] = val;
        kbf[(bh*Tz + t)*DHz + d] = f2bf((float)val);
      }
    }
  }
}

// ---- V GEMM in f32: columns [2048, 3072) ---------------------------------
__global__ __launch_bounds__(256) void v_gemm_f32(
    const float* __restrict__ A, const float* __restrict__ W,
    const float* __restrict__ bias, float* __restrict__ v32)
{
  __shared__ float As[16][68];
  __shared__ float Ws[16][68];
  const int tid = threadIdx.x;
  const int tx = tid & 15, ty = tid >> 4;
  const int m0 = blockIdx.y * 64, n0 = blockIdx.x * 64;
  const int lrow = tid >> 2, lkq = tid & 3;
  float acc[4][4] = {};
  const float* Aload = A + (size_t)(m0 + lrow) * Dz + lkq * 4;
  const float* Wload = W + (size_t)(2*BNz + n0 + lrow) * Dz + lkq * 4;
  for (int kt = 0; kt < Dz; kt += 16) {
    float4 a4 = *(const float4*)(Aload + kt);
    float4 w4 = *(const float4*)(Wload + kt);
    __syncthreads();
    As[lkq*4+0][lrow] = a4.x; As[lkq*4+1][lrow] = a4.y;
    As[lkq*4+2][lrow] = a4.z; As[lkq*4+3][lrow] = a4.w;
    Ws[lkq*4+0][lrow] = w4.x; Ws[lkq*4+1][lrow] = w4.y;
    Ws[lkq*4+2][lrow] = w4.z; Ws[lkq*4+3][lrow] = w4.w;
    __syncthreads();
#pragma unroll
    for (int k = 0; k < 16; ++k) {
      float4 av = *(const float4*)&As[k][ty*4];
      float4 wv = *(const float4*)&Ws[k][tx*4];
      float a_[4] = {av.x, av.y, av.z, av.w};
      float w_[4] = {wv.x, wv.y, wv.z, wv.w};
#pragma unroll
      for (int i = 0; i < 4; ++i)
#pragma unroll
        for (int j = 0; j < 4; ++j)
          acc[i][j] = fmaf(a_[i], w_[j], acc[i][j]);
    }
  }
#pragma unroll
  for (int i = 0; i < 4; ++i) {
    int m = m0 + ty*4 + i;
    int bb = m / Tz, t = m % Tz;
#pragma unroll
    for (int j = 0; j < 4; ++j) {
      int n = n0 + tx*4 + j;
      float val = acc[i][j] + bias[2*BNz + n];
      int h = n >> 6, d = n & 63;
      v32[(((size_t)(bb*Hz + h))*Tz + t)*DHz + d] = val;
    }
  }
}

// ---- proj GEMM f32 -------------------------------------------------------
__global__ __launch_bounds__(256) void proj_gemm(
    const float* __restrict__ A, const float* __restrict__ W,
    const float* __restrict__ bias, float* __restrict__ out)
{
  __shared__ float As[16][68];
  __shared__ float Ws[16][68];
  const int tid = threadIdx.x;
  const int tx = tid & 15, ty = tid >> 4;
  const int m0 = blockIdx.y * 64, n0 = blockIdx.x * 64;
  const int lrow = tid >> 2, lkq = tid & 3;
  float acc[4][4] = {};
  const float* Aload = A + (size_t)(m0 + lrow) * Dz + lkq * 4;
  const float* Wload = W + (size_t)(n0 + lrow) * Dz + lkq * 4;
  for (int kt = 0; kt < Dz; kt += 16) {
    float4 a4 = *(const float4*)(Aload + kt);
    float4 w4 = *(const float4*)(Wload + kt);
    __syncthreads();
    As[lkq*4+0][lrow] = a4.x; As[lkq*4+1][lrow] = a4.y;
    As[lkq*4+2][lrow] = a4.z; As[lkq*4+3][lrow] = a4.w;
    Ws[lkq*4+0][lrow] = w4.x; Ws[lkq*4+1][lrow] = w4.y;
    Ws[lkq*4+2][lrow] = w4.z; Ws[lkq*4+3][lrow] = w4.w;
    __syncthreads();
#pragma unroll
    for (int k = 0; k < 16; ++k) {
      float4 av = *(const float4*)&As[k][ty*4];
      float4 wv = *(const float4*)&Ws[k][tx*4];
      float a_[4] = {av.x, av.y, av.z, av.w};
      float w_[4] = {wv.x, wv.y, wv.z, wv.w};
#pragma unroll
      for (int i = 0; i < 4; ++i)
#pragma unroll
        for (int j = 0; j < 4; ++j)
          acc[i][j] = fmaf(a_[i], w_[j], acc[i][j]);
    }
  }
#pragma unroll
  for (int i = 0; i < 4; ++i) {
    int m = m0 + ty*4 + i;
#pragma unroll
    for (int j = 0; j < 4; ++j) {
      int n = n0 + tx*4 + j;
      out[(size_t)m * Dz + n] = acc[i][j] + bias[n];
    }
  }
}

// ---- attention v5: 512 threads / 8 waves; register-resident screen
//      (64 VGPR scores/lane), atomic-free bisection cut, register collect,
//      32-lane-per-row f64 rescore -> exact tie-aware rank-64 +
//      ambiguity-band blending (selection semantics identical to r5-r9).
__global__ __launch_bounds__(512, 4) void attn_topk(
    const double* __restrict__ q64g, const double* __restrict__ k64g,
    const short* __restrict__ kbfg, const float* __restrict__ v32,
    float* __restrict__ y)
{
  __shared__ __align__(32) double q64_s[QBLK][DHz];        // 8 KB
  __shared__ float candv[QBLK*CAND_MAX];                   // 14 KB
  __shared__ unsigned short candidx[QBLK*CAND_MAX];        // 7 KB
  __shared__ float kp[QBLK][KEEP_MAX];                     // 6 KB
  __shared__ unsigned short ki[QBLK][KEEP_MAX];            // 3 KB
  __shared__ float rcut[QBLK], rlo[QBLK], rhi[QBLK];
  __shared__ int rcnt[QBLK], rdone[QBLK], ndone;
  __shared__ float threshf[QBLK], mrowf[QBLK];
  __shared__ int candcnt[QBLK], keptcnt[QBLK];
  __shared__ float wband[QBLK], denom[QBLK], rdenom[QBLK];

  const int tid = threadIdx.x;
  // XCD-locality swizzle [T1, validated r9]: all 128 q-blocks of one (b,h)
  // land on one XCD; resident blocks per XCD share one K/V/Q panel in L2.
  // grid = 2048 blocks; xcd = bid % 8 (HW round-robin).
  const int bid0 = blockIdx.x;
  const int bh_idx = (bid0 & 7) + 8 * (bid0 >> 8);    // 0..31  (2048 = 8*256)
  const int qb2 = (bid0 >> 3) & 63;                   // 0..63 (two q-blocks each)
  const int h = bh_idx & 15;
  const int bb = bh_idx >> 4;
  const size_t bh = (size_t)(bb * Hz + h);
  const int qb = qb2 * 2 + 0;  // this block handles q rows [qb2*32, qb2*32+16)
  // NOTE: grid halved by doubling rows? No — keep 16 rows/block, 4096 blocks.
  (void)qb;
  // Recompute for 4096-block grid: bh_idx = (bid&7)+8*(bid>>9) over 4096=8*512
  const int bh_i = (bid0 & 7) + 8 * (bid0 >> 9);      // 0..31
  const int qb_i = (bid0 >> 3) & 63;                  // 0..63? 4096/8/32... see launch
  (void)bh_i; (void)qb_i;
  // Final (launch uses 4096 blocks): decode as in r9.
  const int bh_f = (bid0 & 7) + 8 * (bid0 >> 10);     // 0..31
  const int qbf = (bid0 >> 3) & 127;                  // 0..127
  const int hF = bh_f & 15;
  const int bbF = bh_f >> 4;
  const size_t bhF = (size_t)(bbF * Hz + hF);
  const double* qg = q64g + (bhF * Tz + (size_t)qbf * QBLK) * DHz;
  const double* kg64 = k64g + bhF * Tz * DHz;
  const short* kb = kbfg + bhF * Tz * DHz;
  const float* vg = v32 + bhF * Tz * DHz;

  if (tid < QBLK) {
    denom[tid] = 0.f; candcnt[tid] = 0; keptcnt[tid] = 0;
    rlo[tid] = -21.0f; rhi[tid] = 21.0f; rcut[tid] = 0.0f;
    rcnt[tid] = 0; rdone[tid] = 0;
  }
  if (tid == 0) ndone = 0;
  {
    int r = tid >> 5, d2 = (tid & 31) * 2;
    double2 qv = *(const double2*)&qg[r*DHz + d2];
    q64_s[r][d2+0] = qv.x; q64_s[r][d2+1] = qv.y;
  }
  __syncthreads();

  // ---- MFMA screen: wave w owns columns [w*256, w*256+256), 16 tiles ----
  const int lane = tid & 63;
  const int wid = tid >> 6;           // 0..7
  const int bcol = lane & 15;
  const int lgrp = lane >> 4;         // C rows = lgrp*4 + j
  bf16x8 aF0, aF1;
#pragma unroll
  for (int e = 0; e < 8; ++e) {
    aF0[e] = f2bf((float)q64_s[bcol][lgrp*8 + e]);
    aF1[e] = f2bf((float)q64_s[bcol][32 + lgrp*8 + e]);
  }
  const int t0base = wid * 256;

  float sc[16][4];                    // 64 VGPR, statically indexed
#pragma unroll
  for (int tt = 0; tt < 16; ++tt) {
    const short* kbp = kb + (size_t)(t0base + tt*16 + bcol) * DHz;
    bf16x8 b0 = *(const bf16x8*)(kbp + lgrp*8);
    bf16x8 b1 = *(const bf16x8*)(kbp + 32 + lgrp*8);
    f32x4 c = {0.f, 0.f, 0.f, 0.f};
    c = __builtin_amdgcn_mfma_f32_16x16x32_bf16(aF0, b0, c, 0, 0, 0);
    c = __builtin_amdgcn_mfma_f32_16x16x32_bf16(aF1, b1, c, 0, 0, 0);
#pragma unroll
    for (int j = 0; j < 4; ++j) sc[tt][j] = c[j];
  }

  // ---- atomic-free bisection for per-row cut with count in [64, CNT_HI] ----
  for (int it = 0; it < BIS_ITERS; ++it) {
    float tj[4];
#pragma unroll
    for (int j = 0; j < 4; ++j) tj[j] = rcut[lgrp*4 + j];
    int cnt[4] = {0, 0, 0, 0};
#pragma unroll
    for (int tt = 0; tt < 16; ++tt)
#pragma unroll
      for (int j = 0; j < 4; ++j)
        cnt[j] += (sc[tt][j] >= tj[j]) ? 1 : 0;
#pragma unroll
    for (int m = 1; m < 16; m <<= 1)
#pragma unroll
      for (int j = 0; j < 4; ++j) cnt[j] += __shfl_xor(cnt[j], m);
    if (bcol == 0) {
#pragma unroll
      for (int j = 0; j < 4; ++j) {
        int r = lgrp*4 + j;
        if (!rdone[r]) atomicAdd(&rcnt[r], cnt[j]);
      }
    }
    __syncthreads();
    if (tid < QBLK && !rdone[tid]) {
      int c = rcnt[tid]; rcnt[tid] = 0;
      if (c >= TOPKz && c <= CNT_HI) {
        rdone[tid] = 1; atomicAdd(&ndone, 1);
      } else {
        if (c >= TOPKz) rlo[tid] = rcut[tid]; else rhi[tid] = rcut[tid];
        rcut[tid] = 0.5f * (rlo[tid] + rhi[tid]);
      }
    }
    __syncthreads();
    if (ndone == QBLK) break;
  }
  if (tid < QBLK && !rdone[tid]) rcut[tid] = rlo[tid];  // count>=64 guaranteed
  __syncthreads();

  // ---- candidate collection from registers ----
  {
    float cj[4];
#pragma unroll
    for (int j = 0; j < 4; ++j) cj[j] = rcut[lgrp*4 + j] - DELTA;
#pragma unroll
    for (int tt = 0; tt < 16; ++tt) {
#pragma unroll
      for (int j = 0; j < 4; ++j) {
        if (sc[tt][j] >= cj[j]) {
          int r = lgrp*4 + j;
          int p = atomicAdd(&candcnt[r], 1);
          if (p < CAND_MAX) candidx[r*CAND_MAX + p] = (unsigned short)(t0base + tt*16 + bcol);
        }
      }
    }
  }
  __syncthreads();

  // ---- f64 rescore, thread-per-candidate (32 lanes per row) ----
  {
    int r = tid >> 5, l32 = tid & 31;
    int n = candcnt[r]; if (n > CAND_MAX) n = CAND_MAX;
    for (int i = l32; i < n; i += 32) {
      int col = (int)candidx[r*CAND_MAX + i];
      const double* kpd = kg64 + (size_t)col * DHz;
      double s = 0.0;
#pragma unroll
      for (int d = 0; d < DHz; d += 4) {
        double4 k4 = *(const double4*)(kpd + d);
        s = fma(q64_s[r][d+0], k4.x, s);
        s = fma(q64_s[r][d+1], k4.y, s);
        s = fma(q64_s[r][d+2], k4.z, s);
        s = fma(q64_s[r][d+3], k4.w, s);
      }
      candv[r*CAND_MAX + i] = (float)s;     // f32 ulp 5e-7 << BAND
    }
  }
  __syncthreads();

  // ---- exact rank-64 threshold (tie-aware) + row max, f32 ----
  {
    int r = tid >> 5, l32 = tid & 31;
    int n = candcnt[r]; if (n > CAND_MAX) n = CAND_MAX;
    float best = -3.0e38f, mx = -3.0e38f;
    for (int i = l32; i < n; i += 32) {
      float x = candv[r*CAND_MAX + i];
      mx = fmaxf(mx, x);
      int cnt = 0;
      for (int j = 0; j < n; ++j) cnt += (candv[r*CAND_MAX + j] >= x) ? 1 : 0;
      if (cnt >= TOPKz && x > best) best = x;
    }
#pragma unroll
    for (int m = 1; m < 32; m <<= 1) {
      best = fmaxf(best, __shfl_xor(best, m));
      mx   = fmaxf(mx,   __shfl_xor(mx, m));
    }
    if (l32 == 0) { threshf[r] = best; mrowf[r] = mx; }
  }
  __syncthreads();

  // ---- ambiguity band stats ----
  {
    int r = tid >> 5, l32 = tid & 31;
    int n = candcnt[r]; if (n > CAND_MAX) n = CAND_MAX;
    float T = threshf[r];
    int na = 0, nb = 0;
    for (int i = l32; i < n; i += 32) {
      float s = candv[r*CAND_MAX + i];
      if (s > T + BAND) na++;
      else if (s >= T - BAND) nb++;
    }
#pragma unroll
    for (int m = 1; m < 32; m <<= 1) {
      na += __shfl_xor(na, m);
      nb += __shfl_xor(nb, m);
    }
    if (l32 == 0) wband[r] = (float)(TOPKz - na) / (float)(nb > 0 ? nb : 1);
  }
  __syncthreads();

  // ---- kept set + weighted softmax numerators ----
  {
    int r = tid >> 5, l32 = tid & 31;
    int n = candcnt[r]; if (n > CAND_MAX) n = CAND_MAX;
    float T = threshf[r], mx = mrowf[r];
    float wb = wband[r];
    float lsum = 0.f;
    for (int i = l32; i < n; i += 32) {
      float s = candv[r*CAND_MAX + i];
      float w = (s > T + BAND) ? 1.f : ((s >= T - BAND) ? wb : 0.f);
      if (w > 0.f) {
        float p = w * expf((s - mx) * 0.125f);
        int pos = atomicAdd(&keptcnt[r], 1);
        if (pos < KEEP_MAX) { kp[r][pos] = p; ki[r][pos] = candidx[r*CAND_MAX + i]; lsum += p; }
      }
    }
    if (lsum != 0.f) atomicAdd(&denom[r], lsum);
  }
  __syncthreads();
  if (tid < QBLK) rdenom[tid] = 1.0f / denom[tid];
  __syncthreads();

  // ---- sparse AV: thread = (row, 2 dims) ----
  {
    int r = tid >> 5, d0 = (tid & 31) * 2;
    int n = keptcnt[r]; if (n > KEEP_MAX) n = KEEP_MAX;
    float rd = rdenom[r];
    float2 o = make_float2(0.f, 0.f);
    for (int i = 0; i < n; ++i) {
      float p = kp[r][i] * rd;
      int idx = (int)ki[r][i];
      float2 vv = *(const float2*)&vg[(size_t)idx*DHz + d0];
      o.x = fmaf(p, vv.x, o.x);
      o.y = fmaf(p, vv.y, o.y);
    }
    float* yo = y + ((size_t)bbF*Tz + (size_t)qbf*QBLK + r) * BNz + hF*DHz + d0;
    *(float2*)yo = o;
  }
}

extern "C" void kernel_launch(void* const* d_in, const int* in_sizes, int n_in,
                              void* d_out, int out_size, void* d_ws, size_t ws_size,
                              hipStream_t stream)
{
  const float* x      = (const float*)d_in[0];
  const float* w_qkv  = (const float*)d_in[1];
  const float* b_qkv  = (const float*)d_in[2];
  const float* w_proj = (const float*)d_in[3];
  const float* b_proj = (const float*)d_in[4];
  float* out = (float*)d_out;

  const size_t E = (size_t)Bz * Hz * Tz * DHz;   // 4,194,304
  double* q64 = (double*)d_ws;                   // 32 MB
  double* k64 = q64 + E;                         // 32 MB
  short* kbf  = (short*)(k64 + E);               // 8 MB (bf16 K)
  float* v32  = (float*)(kbf + E);               // 16 MB
  float* y    = v32 + E;                         // 16 MB  (total 104 MB)

  qk_gemm_f64<<<dim3((2*BNz)/64, (Bz*Tz)/64), 256, 0, stream>>>(x, w_qkv, b_qkv, q64, k64, kbf);
  v_gemm_f32<<<dim3(BNz/64, (Bz*Tz)/64), 256, 0, stream>>>(x, w_qkv, b_qkv, v32);
  attn_topk<<<Bz*Hz*(Tz/QBLK), 512, 0, stream>>>(q64, k64, kbf, v32, y);
  proj_gemm<<<dim3(Dz/64, (Bz*Tz)/64), 256, 0, stream>>>(y, w_proj, b_proj, out);
}

// Round 11
// 1390.877 us; speedup vs baseline: 1.3186x; 1.3186x over previous
//
#include <hip/hip_runtime.h>
#include <hip/hip_bf16.h>
#include <math.h>

#define Bz 2
#define Tz 2048
#define Dz 1024
#define Hz 16
#define DHz 64
#define BNz 1024
#define TOPKz 64
#define QBLK 16
#define CAND_MAX 176
#define KEEP_MAX 96
#define DELTA 0.35f   // >= 2x bf16-screen error bound (validated r6-r10)
#define BAND 8e-5f    // ambiguity half-band on RAW scores (verified r5-r10)
#define SLO  -20.0f   // fixed histogram range [-20,20): 6.1 sigma of N(0,3.3)
#define SBINW 0.15625f   // 40/256
#define SBINR 6.4f       // 1/SBINW

typedef __attribute__((ext_vector_type(8))) short bf16x8;
typedef __attribute__((ext_vector_type(4))) float f32x4;

__device__ __forceinline__ short f2bf(float f) {     // RNE f32 -> bf16
  unsigned u = __float_as_uint(f);
  return (short)((u + 0x7FFFu + ((u >> 16) & 1u)) >> 16);
}

// ---- QK GEMM in f64: columns [0, 2048). Writes q64, k64 (t-major) and
//      kbf (bf16 K panel, t-major, for the MFMA screen). -------------------
__global__ __launch_bounds__(256) void qk_gemm_f64(
    const float* __restrict__ A, const float* __restrict__ W,
    const float* __restrict__ bias,
    double* __restrict__ q64, double* __restrict__ k64, short* __restrict__ kbf)
{
  __shared__ __align__(32) double As[16][68];
  __shared__ __align__(32) double Ws[16][68];
  const int tid = threadIdx.x;
  const int tx = tid & 15, ty = tid >> 4;
  const int m0 = blockIdx.y * 64, n0 = blockIdx.x * 64;
  const int lrow = tid >> 2, lkq = tid & 3;
  double acc[4][4] = {};
  const float* Aload = A + (size_t)(m0 + lrow) * Dz + lkq * 4;
  const float* Wload = W + (size_t)(n0 + lrow) * Dz + lkq * 4;
  for (int kt = 0; kt < Dz; kt += 16) {
    float4 a4 = *(const float4*)(Aload + kt);
    float4 w4 = *(const float4*)(Wload + kt);
    __syncthreads();
    As[lkq*4+0][lrow] = (double)a4.x; As[lkq*4+1][lrow] = (double)a4.y;
    As[lkq*4+2][lrow] = (double)a4.z; As[lkq*4+3][lrow] = (double)a4.w;
    Ws[lkq*4+0][lrow] = (double)w4.x; Ws[lkq*4+1][lrow] = (double)w4.y;
    Ws[lkq*4+2][lrow] = (double)w4.z; Ws[lkq*4+3][lrow] = (double)w4.w;
    __syncthreads();
#pragma unroll
    for (int k = 0; k < 16; ++k) {
      double4 av = *(const double4*)&As[k][ty*4];
      double4 wv = *(const double4*)&Ws[k][tx*4];
      double a_[4] = {av.x, av.y, av.z, av.w};
      double w_[4] = {wv.x, wv.y, wv.z, wv.w};
#pragma unroll
      for (int i = 0; i < 4; ++i)
#pragma unroll
        for (int j = 0; j < 4; ++j)
          acc[i][j] = fma(a_[i], w_[j], acc[i][j]);
    }
  }
#pragma unroll
  for (int i = 0; i < 4; ++i) {
    int m = m0 + ty*4 + i;
    int bb = m / Tz, t = m % Tz;
#pragma unroll
    for (int j = 0; j < 4; ++j) {
      int n = n0 + tx*4 + j;
      double val = acc[i][j] + (double)bias[n];
      if (n < BNz) {
        int h = n >> 6, d = n & 63;
        q64[(((size_t)(bb*Hz + h))*Tz + t)*DHz + d] = val;
      } else {
        int h = (n - BNz) >> 6, d = n & 63;
        size_t bh = (size_t)(bb*Hz + h);
        k64[(bh*Tz + t)*DHz + d] = val;
        kbf[(bh*Tz + t)*DHz + d] = f2bf((float)val);
      }
    }
  }
}

// ---- V GEMM in f32: columns [2048, 3072) ---------------------------------
__global__ __launch_bounds__(256) void v_gemm_f32(
    const float* __restrict__ A, const float* __restrict__ W,
    const float* __restrict__ bias, float* __restrict__ v32)
{
  __shared__ float As[16][68];
  __shared__ float Ws[16][68];
  const int tid = threadIdx.x;
  const int tx = tid & 15, ty = tid >> 4;
  const int m0 = blockIdx.y * 64, n0 = blockIdx.x * 64;
  const int lrow = tid >> 2, lkq = tid & 3;
  float acc[4][4] = {};
  const float* Aload = A + (size_t)(m0 + lrow) * Dz + lkq * 4;
  const float* Wload = W + (size_t)(2*BNz + n0 + lrow) * Dz + lkq * 4;
  for (int kt = 0; kt < Dz; kt += 16) {
    float4 a4 = *(const float4*)(Aload + kt);
    float4 w4 = *(const float4*)(Wload + kt);
    __syncthreads();
    As[lkq*4+0][lrow] = a4.x; As[lkq*4+1][lrow] = a4.y;
    As[lkq*4+2][lrow] = a4.z; As[lkq*4+3][lrow] = a4.w;
    Ws[lkq*4+0][lrow] = w4.x; Ws[lkq*4+1][lrow] = w4.y;
    Ws[lkq*4+2][lrow] = w4.z; Ws[lkq*4+3][lrow] = w4.w;
    __syncthreads();
#pragma unroll
    for (int k = 0; k < 16; ++k) {
      float4 av = *(const float4*)&As[k][ty*4];
      float4 wv = *(const float4*)&Ws[k][tx*4];
      float a_[4] = {av.x, av.y, av.z, av.w};
      float w_[4] = {wv.x, wv.y, wv.z, wv.w};
#pragma unroll
      for (int i = 0; i < 4; ++i)
#pragma unroll
        for (int j = 0; j < 4; ++j)
          acc[i][j] = fmaf(a_[i], w_[j], acc[i][j]);
    }
  }
#pragma unroll
  for (int i = 0; i < 4; ++i) {
    int m = m0 + ty*4 + i;
    int bb = m / Tz, t = m % Tz;
#pragma unroll
    for (int j = 0; j < 4; ++j) {
      int n = n0 + tx*4 + j;
      float val = acc[i][j] + bias[2*BNz + n];
      int h = n >> 6, d = n & 63;
      v32[(((size_t)(bb*Hz + h))*Tz + t)*DHz + d] = val;
    }
  }
}

// ---- proj GEMM f32 -------------------------------------------------------
__global__ __launch_bounds__(256) void proj_gemm(
    const float* __restrict__ A, const float* __restrict__ W,
    const float* __restrict__ bias, float* __restrict__ out)
{
  __shared__ float As[16][68];
  __shared__ float Ws[16][68];
  const int tid = threadIdx.x;
  const int tx = tid & 15, ty = tid >> 4;
  const int m0 = blockIdx.y * 64, n0 = blockIdx.x * 64;
  const int lrow = tid >> 2, lkq = tid & 3;
  float acc[4][4] = {};
  const float* Aload = A + (size_t)(m0 + lrow) * Dz + lkq * 4;
  const float* Wload = W + (size_t)(n0 + lrow) * Dz + lkq * 4;
  for (int kt = 0; kt < Dz; kt += 16) {
    float4 a4 = *(const float4*)(Aload + kt);
    float4 w4 = *(const float4*)(Wload + kt);
    __syncthreads();
    As[lkq*4+0][lrow] = a4.x; As[lkq*4+1][lrow] = a4.y;
    As[lkq*4+2][lrow] = a4.z; As[lkq*4+3][lrow] = a4.w;
    Ws[lkq*4+0][lrow] = w4.x; Ws[lkq*4+1][lrow] = w4.y;
    Ws[lkq*4+2][lrow] = w4.z; Ws[lkq*4+3][lrow] = w4.w;
    __syncthreads();
#pragma unroll
    for (int k = 0; k < 16; ++k) {
      float4 av = *(const float4*)&As[k][ty*4];
      float4 wv = *(const float4*)&Ws[k][tx*4];
      float a_[4] = {av.x, av.y, av.z, av.w};
      float w_[4] = {wv.x, wv.y, wv.z, wv.w};
#pragma unroll
      for (int i = 0; i < 4; ++i)
#pragma unroll
        for (int j = 0; j < 4; ++j)
          acc[i][j] = fmaf(a_[i], w_[j], acc[i][j]);
    }
  }
#pragma unroll
  for (int i = 0; i < 4; ++i) {
    int m = m0 + ty*4 + i;
#pragma unroll
    for (int j = 0; j < 4; ++j) {
      int n = n0 + tx*4 + j;
      out[(size_t)m * Dz + n] = acc[i][j] + bias[n];
    }
  }
}

// ---- attention v6 = r9 structure, spill-free.
//      NO launch_bounds occupancy cap (the r8-r10 `,4` forced VGPR=64 and
//      spilled ~80-130 MB/dispatch to scratch — WRITE_SIZE 98/229 MB vs
//      16 MB ideal). Fixed-range histogram (1 MFMA pass, unroll-4) -> cut ->
//      collect (2nd pass, unroll-4) -> thread-parallel f64 rescore ->
//      exact tie-aware rank-64 + ambiguity-band blending (semantics r5-r10).
__global__ __launch_bounds__(256) void attn_topk(
    const double* __restrict__ q64g, const double* __restrict__ k64g,
    const short* __restrict__ kbfg, const float* __restrict__ v32,
    float* __restrict__ y)
{
  __shared__ __align__(32) double q64_s[QBLK][DHz];        // 8 KB
  __shared__ __align__(16) unsigned char ubuf[QBLK*CAND_MAX*6];  // 16.5 KB
  __shared__ float kp[QBLK][KEEP_MAX];                     // 6 KB
  __shared__ unsigned short ki[QBLK][KEEP_MAX];            // 3 KB
  __shared__ float cutlo[QBLK], threshf[QBLK], mrowf[QBLK];
  __shared__ int candcnt[QBLK], keptcnt[QBLK];
  __shared__ float wband[QBLK], denom[QBLK], rdenom[QBLK];

  unsigned* hist = (unsigned*)ubuf;                        // [16][256]
  float* candv = (float*)ubuf;                             // [16][CAND_MAX]
  unsigned short* candidx = (unsigned short*)(ubuf + QBLK*CAND_MAX*4);

  const int tid = threadIdx.x;
  // XCD-locality swizzle [T1, validated r9: FETCH 501->82 MB]: all 128
  // q-blocks of one (b,h) land on one XCD; its K/V/Q panels (~2.8 MB) stay
  // hot in that XCD's 4 MB L2. Bijective on [0,4096).
  const int bid0 = blockIdx.x;
  const int bh_f = (bid0 & 7) + 8 * (bid0 >> 10);     // 0..31
  const int qbf = (bid0 >> 3) & 127;                  // 0..127
  const int h = bh_f & 15;
  const int bb = bh_f >> 4;
  const size_t bh = (size_t)(bb * Hz + h);
  const double* qg = q64g + (bh * Tz + (size_t)qbf * QBLK) * DHz;
  const double* kg64 = k64g + bh * Tz * DHz;
  const short* kb = kbfg + bh * Tz * DHz;
  const float* vg = v32 + bh * Tz * DHz;

  if (tid < QBLK) { denom[tid] = 0.f; candcnt[tid] = 0; keptcnt[tid] = 0; }
  for (int i = tid; i < QBLK*256; i += 256) hist[i] = 0u;
  {
    int r = tid >> 4, d4 = (tid & 15) * 4;
    double4 qv = *(const double4*)&qg[r*DHz + d4];
    q64_s[r][d4+0] = qv.x; q64_s[r][d4+1] = qv.y;
    q64_s[r][d4+2] = qv.z; q64_s[r][d4+3] = qv.w;
  }
  __syncthreads();

  // ---- MFMA A-fragments (Q tile; identical A/B lane map, verified r6-r10)
  const int lane = tid & 63;
  const int wid = tid >> 6;
  const int bcol = lane & 15;   // B-col within 16-tile (and C col)
  const int lgrp = lane >> 4;   // k-group; C rows = lgrp*4 + j
  bf16x8 aF0, aF1;
#pragma unroll
  for (int e = 0; e < 8; ++e) {
    aF0[e] = f2bf((float)q64_s[bcol][lgrp*8 + e]);
    aF1[e] = f2bf((float)q64_s[bcol][32 + lgrp*8 + e]);
  }
  const int t0base = wid * 512;

  // ---- pass 1: scores -> fixed-range histogram (unroll 4: overlap loads) ----
#pragma unroll 4
  for (int tt = 0; tt < 32; ++tt) {
    const short* kbp = kb + (size_t)(t0base + tt*16 + bcol) * DHz;
    bf16x8 b0 = *(const bf16x8*)(kbp + lgrp*8);
    bf16x8 b1 = *(const bf16x8*)(kbp + 32 + lgrp*8);
    f32x4 c = {0.f, 0.f, 0.f, 0.f};
    c = __builtin_amdgcn_mfma_f32_16x16x32_bf16(aF0, b0, c, 0, 0, 0);
    c = __builtin_amdgcn_mfma_f32_16x16x32_bf16(aF1, b1, c, 0, 0, 0);
#pragma unroll
    for (int j = 0; j < 4; ++j) {
      int bin = (int)((c[j] - SLO) * SBINR);
      bin = bin < 0 ? 0 : (bin > 255 ? 255 : bin);
      atomicAdd(&hist[(lgrp*4 + j)*256 + bin], 1u);
    }
  }
  __syncthreads();

  // ---- cut: lower edge of crossing bin - DELTA (16 threads) ----
  if (tid < QBLK) {
    int cum = 0, b = 0;
    for (int x = 255; x >= 0; --x) {
      cum += (int)hist[tid*256 + x];
      if (cum >= TOPKz) { b = x; break; }
    }
    cutlo[tid] = (SLO + (float)b * SBINW) - DELTA;
  }
  __syncthreads();   // hist dead; ubuf becomes candv/candidx

  // ---- pass 2: recompute scores, collect candidates (unroll 4) ----
#pragma unroll 4
  for (int tt = 0; tt < 32; ++tt) {
    const short* kbp = kb + (size_t)(t0base + tt*16 + bcol) * DHz;
    bf16x8 b0 = *(const bf16x8*)(kbp + lgrp*8);
    bf16x8 b1 = *(const bf16x8*)(kbp + 32 + lgrp*8);
    f32x4 c = {0.f, 0.f, 0.f, 0.f};
    c = __builtin_amdgcn_mfma_f32_16x16x32_bf16(aF0, b0, c, 0, 0, 0);
    c = __builtin_amdgcn_mfma_f32_16x16x32_bf16(aF1, b1, c, 0, 0, 0);
#pragma unroll
    for (int j = 0; j < 4; ++j) {
      int r = lgrp*4 + j;
      if (c[j] >= cutlo[r]) {
        int p = atomicAdd(&candcnt[r], 1);
        if (p < CAND_MAX) candidx[r*CAND_MAX + p] = (unsigned short)(t0base + tt*16 + bcol);
      }
    }
  }
  __syncthreads();

  // ---- f64 rescore, thread-per-candidate (16-lane group per row) ----
  {
    int r = tid >> 4, l16 = tid & 15;
    int n = candcnt[r]; if (n > CAND_MAX) n = CAND_MAX;
    for (int i = l16; i < n; i += 16) {
      int col = (int)candidx[r*CAND_MAX + i];
      const double* kpd = kg64 + (size_t)col * DHz;
      double s = 0.0;
#pragma unroll
      for (int d = 0; d < DHz; d += 4) {
        double4 k4 = *(const double4*)(kpd + d);
        s = fma(q64_s[r][d+0], k4.x, s);
        s = fma(q64_s[r][d+1], k4.y, s);
        s = fma(q64_s[r][d+2], k4.z, s);
        s = fma(q64_s[r][d+3], k4.w, s);
      }
      candv[r*CAND_MAX + i] = (float)s;     // f32 ulp 5e-7 << BAND
    }
  }
  __syncthreads();

  // ---- exact rank-64 threshold (tie-aware) + row max, f32 ----
  {
    int r = tid >> 4, l16 = tid & 15;
    int n = candcnt[r]; if (n > CAND_MAX) n = CAND_MAX;
    float best = -3.0e38f, mx = -3.0e38f;
    for (int i = l16; i < n; i += 16) {
      float x = candv[r*CAND_MAX + i];
      mx = fmaxf(mx, x);
      int cnt = 0;
      for (int j = 0; j < n; ++j) cnt += (candv[r*CAND_MAX + j] >= x) ? 1 : 0;
      if (cnt >= TOPKz && x > best) best = x;
    }
#pragma unroll
    for (int m = 1; m < 16; m <<= 1) {
      best = fmaxf(best, __shfl_xor(best, m));
      mx   = fmaxf(mx,   __shfl_xor(mx, m));
    }
    if (l16 == 0) { threshf[r] = best; mrowf[r] = mx; }
  }
  __syncthreads();

  // ---- ambiguity band stats ----
  {
    int r = tid >> 4, l16 = tid & 15;
    int n = candcnt[r]; if (n > CAND_MAX) n = CAND_MAX;
    float T = threshf[r];
    int na = 0, nb = 0;
    for (int i = l16; i < n; i += 16) {
      float s = candv[r*CAND_MAX + i];
      if (s > T + BAND) na++;
      else if (s >= T - BAND) nb++;
    }
#pragma unroll
    for (int m = 1; m < 16; m <<= 1) {
      na += __shfl_xor(na, m);
      nb += __shfl_xor(nb, m);
    }
    if (l16 == 0) wband[r] = (float)(TOPKz - na) / (float)(nb > 0 ? nb : 1);
  }
  __syncthreads();

  // ---- kept set + weighted softmax numerators ----
  {
    int r = tid >> 4, l16 = tid & 15;
    int n = candcnt[r]; if (n > CAND_MAX) n = CAND_MAX;
    float T = threshf[r], mx = mrowf[r];
    float wb = wband[r];
    float lsum = 0.f;
    for (int i = l16; i < n; i += 16) {
      float s = candv[r*CAND_MAX + i];
      float w = (s > T + BAND) ? 1.f : ((s >= T - BAND) ? wb : 0.f);
      if (w > 0.f) {
        float p = w * expf((s - mx) * 0.125f);
        int pos = atomicAdd(&keptcnt[r], 1);
        if (pos < KEEP_MAX) { kp[r][pos] = p; ki[r][pos] = candidx[r*CAND_MAX + i]; lsum += p; }
      }
    }
    if (lsum != 0.f) atomicAdd(&denom[r], lsum);
  }
  __syncthreads();
  if (tid < QBLK) rdenom[tid] = 1.0f / denom[tid];
  __syncthreads();

  // ---- sparse AV ----
  {
    int r = tid >> 4, dg = (tid & 15) * 4;
    int n = keptcnt[r]; if (n > KEEP_MAX) n = KEEP_MAX;
    float rd = rdenom[r];
    float4 o = make_float4(0.f, 0.f, 0.f, 0.f);
    for (int i = 0; i < n; ++i) {
      float p = kp[r][i] * rd;
      int idx = (int)ki[r][i];
      float4 vv = *(const float4*)&vg[(size_t)idx*DHz + dg];
      o.x = fmaf(p, vv.x, o.x);
      o.y = fmaf(p, vv.y, o.y);
      o.z = fmaf(p, vv.z, o.z);
      o.w = fmaf(p, vv.w, o.w);
    }
    float* yo = y + ((size_t)bb*Tz + (size_t)qbf*QBLK + r) * BNz + h*DHz + dg;
    *(float4*)yo = o;
  }
}

extern "C" void kernel_launch(void* const* d_in, const int* in_sizes, int n_in,
                              void* d_out, int out_size, void* d_ws, size_t ws_size,
                              hipStream_t stream)
{
  const float* x      = (const float*)d_in[0];
  const float* w_qkv  = (const float*)d_in[1];
  const float* b_qkv  = (const float*)d_in[2];
  const float* w_proj = (const float*)d_in[3];
  const float* b_proj = (const float*)d_in[4];
  float* out = (float*)d_out;

  const size_t E = (size_t)Bz * Hz * Tz * DHz;   // 4,194,304
  double* q64 = (double*)d_ws;                   // 32 MB
  double* k64 = q64 + E;                         // 32 MB
  short* kbf  = (short*)(k64 + E);               // 8 MB (bf16 K)
  float* v32  = (float*)(kbf + E);               // 16 MB
  float* y    = v32 + E;                         // 16 MB  (total 104 MB)

  qk_gemm_f64<<<dim3((2*BNz)/64, (Bz*Tz)/64), 256, 0, stream>>>(x, w_qkv, b_qkv, q64, k64, kbf);
  v_gemm_f32<<<dim3(BNz/64, (Bz*Tz)/64), 256, 0, stream>>>(x, w_qkv, b_qkv, v32);
  attn_topk<<<Bz*Hz*(Tz/QBLK), 256, 0, stream>>>(q64, k64, kbf, v32, y);
  proj_gemm<<<dim3(Dz/64, (Bz*Tz)/64), 256, 0, stream>>>(y, w_proj, b_proj, out);
}

// Round 12
// 1376.890 us; speedup vs baseline: 1.3320x; 1.0102x over previous
//
#include <hip/hip_runtime.h>
#include <hip/hip_bf16.h>
#include <math.h>

#define Bz 2
#define Tz 2048
#define Dz 1024
#define Hz 16
#define DHz 64
#define BNz 1024
#define TOPKz 64
#define QBLK 16
#define CAND_MAX 176
#define DELTA 0.35f   // >= 2x bf16-screen error bound (validated r6-r11)
#define BAND 8e-5f    // ambiguity half-band on RAW scores (verified r5-r11)
#define SLO  -20.0f   // fixed histogram range [-20,20)
#define SBINW 0.15625f   // 40/256
#define SBINR 6.4f       // 1/SBINW

typedef __attribute__((ext_vector_type(8))) short bf16x8;
typedef __attribute__((ext_vector_type(4))) float f32x4;

__device__ __forceinline__ short f2bf(float f) {     // RNE f32 -> bf16
  unsigned u = __float_as_uint(f);
  return (short)((u + 0x7FFFu + ((u >> 16) & 1u)) >> 16);
}

// ---- QK GEMM in f64: columns [0, 2048). Writes q64, k64 (t-major) and
//      kbf (bf16 K panel, t-major, for the MFMA screen). -------------------
__global__ __launch_bounds__(256) void qk_gemm_f64(
    const float* __restrict__ A, const float* __restrict__ W,
    const float* __restrict__ bias,
    double* __restrict__ q64, double* __restrict__ k64, short* __restrict__ kbf)
{
  __shared__ __align__(32) double As[16][68];
  __shared__ __align__(32) double Ws[16][68];
  const int tid = threadIdx.x;
  const int tx = tid & 15, ty = tid >> 4;
  const int m0 = blockIdx.y * 64, n0 = blockIdx.x * 64;
  const int lrow = tid >> 2, lkq = tid & 3;
  double acc[4][4] = {};
  const float* Aload = A + (size_t)(m0 + lrow) * Dz + lkq * 4;
  const float* Wload = W + (size_t)(n0 + lrow) * Dz + lkq * 4;
  for (int kt = 0; kt < Dz; kt += 16) {
    float4 a4 = *(const float4*)(Aload + kt);
    float4 w4 = *(const float4*)(Wload + kt);
    __syncthreads();
    As[lkq*4+0][lrow] = (double)a4.x; As[lkq*4+1][lrow] = (double)a4.y;
    As[lkq*4+2][lrow] = (double)a4.z; As[lkq*4+3][lrow] = (double)a4.w;
    Ws[lkq*4+0][lrow] = (double)w4.x; Ws[lkq*4+1][lrow] = (double)w4.y;
    Ws[lkq*4+2][lrow] = (double)w4.z; Ws[lkq*4+3][lrow] = (double)w4.w;
    __syncthreads();
#pragma unroll
    for (int k = 0; k < 16; ++k) {
      double4 av = *(const double4*)&As[k][ty*4];
      double4 wv = *(const double4*)&Ws[k][tx*4];
      double a_[4] = {av.x, av.y, av.z, av.w};
      double w_[4] = {wv.x, wv.y, wv.z, wv.w};
#pragma unroll
      for (int i = 0; i < 4; ++i)
#pragma unroll
        for (int j = 0; j < 4; ++j)
          acc[i][j] = fma(a_[i], w_[j], acc[i][j]);
    }
  }
#pragma unroll
  for (int i = 0; i < 4; ++i) {
    int m = m0 + ty*4 + i;
    int bb = m / Tz, t = m % Tz;
#pragma unroll
    for (int j = 0; j < 4; ++j) {
      int n = n0 + tx*4 + j;
      double val = acc[i][j] + (double)bias[n];
      if (n < BNz) {
        int h = n >> 6, d = n & 63;
        q64[(((size_t)(bb*Hz + h))*Tz + t)*DHz + d] = val;
      } else {
        int h = (n - BNz) >> 6, d = n & 63;
        size_t bh = (size_t)(bb*Hz + h);
        k64[(bh*Tz + t)*DHz + d] = val;
        kbf[(bh*Tz + t)*DHz + d] = f2bf((float)val);
      }
    }
  }
}

// ---- V GEMM in f32: columns [2048, 3072) ---------------------------------
__global__ __launch_bounds__(256) void v_gemm_f32(
    const float* __restrict__ A, const float* __restrict__ W,
    const float* __restrict__ bias, float* __restrict__ v32)
{
  __shared__ float As[16][68];
  __shared__ float Ws[16][68];
  const int tid = threadIdx.x;
  const int tx = tid & 15, ty = tid >> 4;
  const int m0 = blockIdx.y * 64, n0 = blockIdx.x * 64;
  const int lrow = tid >> 2, lkq = tid & 3;
  float acc[4][4] = {};
  const float* Aload = A + (size_t)(m0 + lrow) * Dz + lkq * 4;
  const float* Wload = W + (size_t)(2*BNz + n0 + lrow) * Dz + lkq * 4;
  for (int kt = 0; kt < Dz; kt += 16) {
    float4 a4 = *(const float4*)(Aload + kt);
    float4 w4 = *(const float4*)(Wload + kt);
    __syncthreads();
    As[lkq*4+0][lrow] = a4.x; As[lkq*4+1][lrow] = a4.y;
    As[lkq*4+2][lrow] = a4.z; As[lkq*4+3][lrow] = a4.w;
    Ws[lkq*4+0][lrow] = w4.x; Ws[lkq*4+1][lrow] = w4.y;
    Ws[lkq*4+2][lrow] = w4.z; Ws[lkq*4+3][lrow] = w4.w;
    __syncthreads();
#pragma unroll
    for (int k = 0; k < 16; ++k) {
      float4 av = *(const float4*)&As[k][ty*4];
      float4 wv = *(const float4*)&Ws[k][tx*4];
      float a_[4] = {av.x, av.y, av.z, av.w};
      float w_[4] = {wv.x, wv.y, wv.z, wv.w};
#pragma unroll
      for (int i = 0; i < 4; ++i)
#pragma unroll
        for (int j = 0; j < 4; ++j)
          acc[i][j] = fmaf(a_[i], w_[j], acc[i][j]);
    }
  }
#pragma unroll
  for (int i = 0; i < 4; ++i) {
    int m = m0 + ty*4 + i;
    int bb = m / Tz, t = m % Tz;
#pragma unroll
    for (int j = 0; j < 4; ++j) {
      int n = n0 + tx*4 + j;
      float val = acc[i][j] + bias[2*BNz + n];
      int h = n >> 6, d = n & 63;
      v32[(((size_t)(bb*Hz + h))*Tz + t)*DHz + d] = val;
    }
  }
}

// ---- proj GEMM f32 -------------------------------------------------------
__global__ __launch_bounds__(256) void proj_gemm(
    const float* __restrict__ A, const float* __restrict__ W,
    const float* __restrict__ bias, float* __restrict__ out)
{
  __shared__ float As[16][68];
  __shared__ float Ws[16][68];
  const int tid = threadIdx.x;
  const int tx = tid & 15, ty = tid >> 4;
  const int m0 = blockIdx.y * 64, n0 = blockIdx.x * 64;
  const int lrow = tid >> 2, lkq = tid & 3;
  float acc[4][4] = {};
  const float* Aload = A + (size_t)(m0 + lrow) * Dz + lkq * 4;
  const float* Wload = W + (size_t)(n0 + lrow) * Dz + lkq * 4;
  for (int kt = 0; kt < Dz; kt += 16) {
    float4 a4 = *(const float4*)(Aload + kt);
    float4 w4 = *(const float4*)(Wload + kt);
    __syncthreads();
    As[lkq*4+0][lrow] = a4.x; As[lkq*4+1][lrow] = a4.y;
    As[lkq*4+2][lrow] = a4.z; As[lkq*4+3][lrow] = a4.w;
    Ws[lkq*4+0][lrow] = w4.x; Ws[lkq*4+1][lrow] = w4.y;
    Ws[lkq*4+2][lrow] = w4.z; Ws[lkq*4+3][lrow] = w4.w;
    __syncthreads();
#pragma unroll
    for (int k = 0; k < 16; ++k) {
      float4 av = *(const float4*)&As[k][ty*4];
      float4 wv = *(const float4*)&Ws[k][tx*4];
      float a_[4] = {av.x, av.y, av.z, av.w};
      float w_[4] = {wv.x, wv.y, wv.z, wv.w};
#pragma unroll
      for (int i = 0; i < 4; ++i)
#pragma unroll
        for (int j = 0; j < 4; ++j)
          acc[i][j] = fmaf(a_[i], w_[j], acc[i][j]);
    }
  }
#pragma unroll
  for (int i = 0; i < 4; ++i) {
    int m = m0 + ty*4 + i;
#pragma unroll
    for (int j = 0; j < 4; ++j) {
      int n = n0 + tx*4 + j;
      out[(size_t)m * Dz + n] = acc[i][j] + bias[n];
    }
  }
}

// ---- attention v7: 5 barriers total.
//      hist pass -> parallel suffix-scan cut -> collect pass -> [barrier]
//      -> ONE group-local scope: f64 rescore, tie-aware rank-64 (butterfly
//      broadcast), band stats, softmax-p written in-place over candv,
//      denominator via shfl reduce, sparse AV. Selection semantics r5-r11.
__global__ __launch_bounds__(256) void attn_topk(
    const double* __restrict__ q64g, const double* __restrict__ k64g,
    const short* __restrict__ kbfg, const float* __restrict__ v32,
    float* __restrict__ y)
{
  __shared__ __align__(32) double q64_s[QBLK][DHz];        // 8 KB
  __shared__ __align__(16) unsigned char ubuf[QBLK*CAND_MAX*6];  // 16.5 KB
  __shared__ float cutlo[QBLK];
  __shared__ int candcnt[QBLK];

  unsigned* hist = (unsigned*)ubuf;                        // [16][256]
  float* candv = (float*)ubuf;                             // [16][CAND_MAX]
  unsigned short* candidx = (unsigned short*)(ubuf + QBLK*CAND_MAX*4);

  const int tid = threadIdx.x;
  // XCD-locality swizzle [T1, validated r9: FETCH 501->82 MB]
  const int bid0 = blockIdx.x;
  const int bh_f = (bid0 & 7) + 8 * (bid0 >> 10);     // 0..31
  const int qbf = (bid0 >> 3) & 127;                  // 0..127
  const int h = bh_f & 15;
  const int bb = bh_f >> 4;
  const size_t bh = (size_t)(bb * Hz + h);
  const double* qg = q64g + (bh * Tz + (size_t)qbf * QBLK) * DHz;
  const double* kg64 = k64g + bh * Tz * DHz;
  const short* kb = kbfg + bh * Tz * DHz;
  const float* vg = v32 + bh * Tz * DHz;

  if (tid < QBLK) candcnt[tid] = 0;
  for (int i = tid; i < QBLK*256; i += 256) hist[i] = 0u;
  {
    int r = tid >> 4, d4 = (tid & 15) * 4;
    double4 qv = *(const double4*)&qg[r*DHz + d4];
    q64_s[r][d4+0] = qv.x; q64_s[r][d4+1] = qv.y;
    q64_s[r][d4+2] = qv.z; q64_s[r][d4+3] = qv.w;
  }
  __syncthreads();                                    // barrier 1

  // ---- MFMA A-fragments (identical A/B lane map, verified r6-r11) ----
  const int lane = tid & 63;
  const int wid = tid >> 6;
  const int bcol = lane & 15;
  const int lgrp = lane >> 4;
  bf16x8 aF0, aF1;
#pragma unroll
  for (int e = 0; e < 8; ++e) {
    aF0[e] = f2bf((float)q64_s[bcol][lgrp*8 + e]);
    aF1[e] = f2bf((float)q64_s[bcol][32 + lgrp*8 + e]);
  }
  const int t0base = wid * 512;

  // ---- pass 1: scores -> fixed-range histogram ----
#pragma unroll 4
  for (int tt = 0; tt < 32; ++tt) {
    const short* kbp = kb + (size_t)(t0base + tt*16 + bcol) * DHz;
    bf16x8 b0 = *(const bf16x8*)(kbp + lgrp*8);
    bf16x8 b1 = *(const bf16x8*)(kbp + 32 + lgrp*8);
    f32x4 c = {0.f, 0.f, 0.f, 0.f};
    c = __builtin_amdgcn_mfma_f32_16x16x32_bf16(aF0, b0, c, 0, 0, 0);
    c = __builtin_amdgcn_mfma_f32_16x16x32_bf16(aF1, b1, c, 0, 0, 0);
#pragma unroll
    for (int j = 0; j < 4; ++j) {
      int bin = (int)((c[j] - SLO) * SBINR);
      bin = bin < 0 ? 0 : (bin > 255 ? 255 : bin);
      atomicAdd(&hist[(lgrp*4 + j)*256 + bin], 1u);
    }
  }
  __syncthreads();                                    // barrier 2

  // ---- parallel cut: 16-lane suffix scan + ballot per row ----
  {
    int r = tid >> 4, i16 = tid & 15;
    int s = 0;
#pragma unroll
    for (int j = 0; j < 16; ++j) s += (int)hist[r*256 + i16*16 + j];
    int S = s;
#pragma unroll
    for (int off = 1; off < 16; off <<= 1) {
      int src = i16 + off;
      int v = __shfl(S, (lane & 48) | (src < 16 ? src : 15));
      S += (src < 16) ? v : 0;
    }
    unsigned long long blt = __ballot(S >= TOPKz);
    unsigned mask16 = (unsigned)((blt >> (lane & 48)) & 0xFFFFull);
    int istar = 31 - __builtin_clz(mask16);           // mask16 != 0 (total=2048)
    if (i16 == istar) {
      int cum = S - s;
      int b = istar * 16;
      for (int j = 15; j >= 0; --j) {
        cum += (int)hist[r*256 + istar*16 + j];
        if (cum >= TOPKz) { b = istar*16 + j; break; }
      }
      cutlo[r] = (SLO + (float)b * SBINW) - DELTA;
    }
  }
  __syncthreads();                                    // barrier 3 (hist dead)

  // ---- pass 2: recompute scores, collect candidates ----
#pragma unroll 4
  for (int tt = 0; tt < 32; ++tt) {
    const short* kbp = kb + (size_t)(t0base + tt*16 + bcol) * DHz;
    bf16x8 b0 = *(const bf16x8*)(kbp + lgrp*8);
    bf16x8 b1 = *(const bf16x8*)(kbp + 32 + lgrp*8);
    f32x4 c = {0.f, 0.f, 0.f, 0.f};
    c = __builtin_amdgcn_mfma_f32_16x16x32_bf16(aF0, b0, c, 0, 0, 0);
    c = __builtin_amdgcn_mfma_f32_16x16x32_bf16(aF1, b1, c, 0, 0, 0);
#pragma unroll
    for (int j = 0; j < 4; ++j) {
      int r = lgrp*4 + j;
      if (c[j] >= cutlo[r]) {
        int p = atomicAdd(&candcnt[r], 1);
        if (p < CAND_MAX) candidx[r*CAND_MAX + p] = (unsigned short)(t0base + tt*16 + bcol);
      }
    }
  }
  __syncthreads();                                    // barrier 4 (last one)

  // ==== single group-local scope: rescore / rank / band / softmax / AV ====
  {
    const int r = tid >> 4, i16 = tid & 15;
    int n = candcnt[r]; if (n > CAND_MAX) n = CAND_MAX;

    // f64 rescore, thread-per-candidate
    for (int i = i16; i < n; i += 16) {
      int col = (int)candidx[r*CAND_MAX + i];
      const double* kpd = kg64 + (size_t)col * DHz;
      double s = 0.0;
#pragma unroll
      for (int d = 0; d < DHz; d += 4) {
        double4 k4 = *(const double4*)(kpd + d);
        s = fma(q64_s[r][d+0], k4.x, s);
        s = fma(q64_s[r][d+1], k4.y, s);
        s = fma(q64_s[r][d+2], k4.z, s);
        s = fma(q64_s[r][d+3], k4.w, s);
      }
      candv[r*CAND_MAX + i] = (float)s;     // f32 ulp 5e-7 << BAND
    }
    // writes visible within the same wave (group subset of wave)

    // exact tie-aware rank-64 threshold + row max (butterfly -> all lanes)
    float best = -3.0e38f, mx = -3.0e38f;
    for (int i = i16; i < n; i += 16) {
      float x = candv[r*CAND_MAX + i];
      mx = fmaxf(mx, x);
      int cnt = 0;
      for (int j = 0; j < n; ++j) cnt += (candv[r*CAND_MAX + j] >= x) ? 1 : 0;
      if (cnt >= TOPKz && x > best) best = x;
    }
#pragma unroll
    for (int m = 1; m < 16; m <<= 1) {
      best = fmaxf(best, __shfl_xor(best, m));
      mx   = fmaxf(mx,   __shfl_xor(mx, m));
    }
    const float T = best;

    // ambiguity band stats (butterfly -> all lanes)
    int na = 0, nb = 0;
    for (int i = i16; i < n; i += 16) {
      float s = candv[r*CAND_MAX + i];
      if (s > T + BAND) na++;
      else if (s >= T - BAND) nb++;
    }
#pragma unroll
    for (int m = 1; m < 16; m <<= 1) {
      na += __shfl_xor(na, m);
      nb += __shfl_xor(nb, m);
    }
    const float wb = (float)(TOPKz - na) / (float)(nb > 0 ? nb : 1);

    // softmax numerators written in place over candv + denom via shfl
    float lsum = 0.f;
    for (int i = i16; i < n; i += 16) {
      float s = candv[r*CAND_MAX + i];
      float w = (s > T + BAND) ? 1.f : ((s >= T - BAND) ? wb : 0.f);
      float p = (w > 0.f) ? w * expf((s - mx) * 0.125f) : 0.f;
      candv[r*CAND_MAX + i] = p;
      lsum += p;
    }
#pragma unroll
    for (int m = 1; m < 16; m <<= 1) lsum += __shfl_xor(lsum, m);
    const float rd = 1.0f / lsum;

    // sparse AV straight off candv/candidx
    const int dg = i16 * 4;
    float4 o = make_float4(0.f, 0.f, 0.f, 0.f);
    for (int i = 0; i < n; ++i) {
      float p = candv[r*CAND_MAX + i];
      if (p > 0.f) {
        int idx = (int)candidx[r*CAND_MAX + i];
        float4 vv = *(const float4*)&vg[(size_t)idx*DHz + dg];
        float pw = p * rd;
        o.x = fmaf(pw, vv.x, o.x);
        o.y = fmaf(pw, vv.y, o.y);
        o.z = fmaf(pw, vv.z, o.z);
        o.w = fmaf(pw, vv.w, o.w);
      }
    }
    float* yo = y + ((size_t)bb*Tz + (size_t)qbf*QBLK + r) * BNz + h*DHz + dg;
    *(float4*)yo = o;
  }
}

extern "C" void kernel_launch(void* const* d_in, const int* in_sizes, int n_in,
                              void* d_out, int out_size, void* d_ws, size_t ws_size,
                              hipStream_t stream)
{
  const float* x      = (const float*)d_in[0];
  const float* w_qkv  = (const float*)d_in[1];
  const float* b_qkv  = (const float*)d_in[2];
  const float* w_proj = (const float*)d_in[3];
  const float* b_proj = (const float*)d_in[4];
  float* out = (float*)d_out;

  const size_t E = (size_t)Bz * Hz * Tz * DHz;   // 4,194,304
  double* q64 = (double*)d_ws;                   // 32 MB
  double* k64 = q64 + E;                         // 32 MB
  short* kbf  = (short*)(k64 + E);               // 8 MB (bf16 K)
  float* v32  = (float*)(kbf + E);               // 16 MB
  float* y    = v32 + E;                         // 16 MB  (total 104 MB)

  qk_gemm_f64<<<dim3((2*BNz)/64, (Bz*Tz)/64), 256, 0, stream>>>(x, w_qkv, b_qkv, q64, k64, kbf);
  v_gemm_f32<<<dim3(BNz/64, (Bz*Tz)/64), 256, 0, stream>>>(x, w_qkv, b_qkv, v32);
  attn_topk<<<Bz*Hz*(Tz/QBLK), 256, 0, stream>>>(q64, k64, kbf, v32, y);
  proj_gemm<<<dim3(Dz/64, (Bz*Tz)/64), 256, 0, stream>>>(y, w_proj, b_proj, out);
}

// Round 14
// 1001.664 us; speedup vs baseline: 1.8310x; 1.3746x over previous
//
#include <hip/hip_runtime.h>
#include <hip/hip_bf16.h>
#include <math.h>

#define Bz 2
#define Tz 2048
#define Dz 1024
#define Hz 16
#define DHz 64
#define BNz 1024
#define TOPKz 64
#define QBLK 16
#define CAND_MAX 176
#define DELTA 0.35f   // >= 2x bf16-screen error bound (validated r6-r12)
#define BAND 8e-5f    // ambiguity half-band on RAW scores (verified r5-r12)
#define SLO  -20.0f
#define SBINW 0.15625f
#define SBINR 6.4f
#define LDSB 40       // bf16 LDS row stride: 80 B rows (16B-aligned, 2-way bank alias = free)

typedef __attribute__((ext_vector_type(8))) short bf16x8;
typedef __attribute__((ext_vector_type(4))) short s16x4;
typedef __attribute__((ext_vector_type(4))) float f32x4;

__device__ __forceinline__ short f2bf(float f) {     // RNE f32 -> bf16
  unsigned u = __float_as_uint(f);
  return (short)((u + 0x7FFFu + ((u >> 16) & 1u)) >> 16);
}
__device__ __forceinline__ float bf2f(short b) {
  return __uint_as_float(((unsigned)(unsigned short)b) << 16);
}

// ---- QKV GEMM via bf16x3 split on the VERIFIED 16x16x32 bf16 MFMA path.
//      x = hi+mid+lo (residuals exact); 6 product terms -> acc_hi + acc_lo.
//      q/k error ~4e-7 abs -> score deviation ~4e-6 << BAND slack.
//      Writes q64, k64 (f64, t-major), kbf (bf16 K), v32 (f32).
__global__ __launch_bounds__(256) void qkv_gemm_split(
    const float* __restrict__ A, const float* __restrict__ W,
    const float* __restrict__ bias,
    double* __restrict__ q64, double* __restrict__ k64,
    short* __restrict__ kbf, float* __restrict__ v32)
{
  __shared__ __align__(16) short Ah[128][LDSB];
  __shared__ __align__(16) short Am[128][LDSB];
  __shared__ __align__(16) short Al[128][LDSB];
  __shared__ __align__(16) short Bh[64][LDSB];
  __shared__ __align__(16) short Bm[64][LDSB];
  __shared__ __align__(16) short Bl[64][LDSB];   // total 45 KB -> 3 blocks/CU

  const int tid = threadIdx.x;
  const int lane = tid & 63, wid = tid >> 6;
  const int m0 = blockIdx.y * 128, n0 = blockIdx.x * 64;
  const int bcol = lane & 15, lgrp = lane >> 4;

  f32x4 acch[2][4], accl[2][4];
#pragma unroll
  for (int ms = 0; ms < 2; ++ms)
#pragma unroll
    for (int nt = 0; nt < 4; ++nt) {
      acch[ms][nt] = (f32x4){0.f, 0.f, 0.f, 0.f};
      accl[ms][nt] = (f32x4){0.f, 0.f, 0.f, 0.f};
    }

  const int arow = tid >> 1, ak = (tid & 1) * 16;   // A: 128 rows x 32k, 16 f32/thread
  const int brow = tid >> 2, bk = (tid & 3) * 8;    // B: 64 rows x 32k,  8 f32/thread
  const float* Ald = A + (size_t)(m0 + arow) * Dz + ak;
  const float* Wld = W + (size_t)(n0 + brow) * Dz + bk;

  for (int kt = 0; kt < Dz; kt += 32) {
    float4 a4[4], b4[2];
#pragma unroll
    for (int j = 0; j < 4; ++j) a4[j] = *(const float4*)(Ald + kt + 4*j);
#pragma unroll
    for (int j = 0; j < 2; ++j) b4[j] = *(const float4*)(Wld + kt + 4*j);
    __syncthreads();   // prior chunk's frag reads done before overwrite

    // split & store A (16 elems -> 4x short4 per component)
#pragma unroll
    for (int j = 0; j < 4; ++j) {
      float vv[4] = {a4[j].x, a4[j].y, a4[j].z, a4[j].w};
      s16x4 h4, m4, l4;
#pragma unroll
      for (int e = 0; e < 4; ++e) {
        short hh = f2bf(vv[e]);
        float r1 = vv[e] - bf2f(hh);
        short mm = f2bf(r1);
        float r2 = r1 - bf2f(mm);
        h4[e] = hh; m4[e] = mm; l4[e] = f2bf(r2);
      }
      *(s16x4*)&Ah[arow][ak + 4*j] = h4;
      *(s16x4*)&Am[arow][ak + 4*j] = m4;
      *(s16x4*)&Al[arow][ak + 4*j] = l4;
    }
    // split & store B (8 elems -> 2x short4 per component)
#pragma unroll
    for (int j = 0; j < 2; ++j) {
      float vv[4] = {b4[j].x, b4[j].y, b4[j].z, b4[j].w};
      s16x4 h4, m4, l4;
#pragma unroll
      for (int e = 0; e < 4; ++e) {
        short hh = f2bf(vv[e]);
        float r1 = vv[e] - bf2f(hh);
        short mm = f2bf(r1);
        float r2 = r1 - bf2f(mm);
        h4[e] = hh; m4[e] = mm; l4[e] = f2bf(r2);
      }
      *(s16x4*)&Bh[brow][bk + 4*j] = h4;
      *(s16x4*)&Bm[brow][bk + 4*j] = m4;
      *(s16x4*)&Bl[brow][bk + 4*j] = l4;
    }
    __syncthreads();

    // fragments: A row = bcol (lane&15), k = lgrp*8+e — the attn-verified map
    bf16x8 ah[2], am[2], al[2];
#pragma unroll
    for (int ms = 0; ms < 2; ++ms) {
      int rr = wid*32 + ms*16 + bcol;
      ah[ms] = *(const bf16x8*)&Ah[rr][lgrp*8];
      am[ms] = *(const bf16x8*)&Am[rr][lgrp*8];
      al[ms] = *(const bf16x8*)&Al[rr][lgrp*8];
    }
#pragma unroll
    for (int nt = 0; nt < 4; ++nt) {
      int nr = nt*16 + bcol;
      bf16x8 bh = *(const bf16x8*)&Bh[nr][lgrp*8];
      bf16x8 bm = *(const bf16x8*)&Bm[nr][lgrp*8];
      bf16x8 bl = *(const bf16x8*)&Bl[nr][lgrp*8];
#pragma unroll
      for (int ms = 0; ms < 2; ++ms) {
        acch[ms][nt] = __builtin_amdgcn_mfma_f32_16x16x32_bf16(ah[ms], bh, acch[ms][nt], 0, 0, 0);
        accl[ms][nt] = __builtin_amdgcn_mfma_f32_16x16x32_bf16(ah[ms], bm, accl[ms][nt], 0, 0, 0);
        accl[ms][nt] = __builtin_amdgcn_mfma_f32_16x16x32_bf16(am[ms], bh, accl[ms][nt], 0, 0, 0);
        accl[ms][nt] = __builtin_amdgcn_mfma_f32_16x16x32_bf16(am[ms], bm, accl[ms][nt], 0, 0, 0);
        accl[ms][nt] = __builtin_amdgcn_mfma_f32_16x16x32_bf16(ah[ms], bl, accl[ms][nt], 0, 0, 0);
        accl[ms][nt] = __builtin_amdgcn_mfma_f32_16x16x32_bf16(al[ms], bh, accl[ms][nt], 0, 0, 0);
      }
    }
  }

  // epilogue: D col = lane&15, row = (lane>>4)*4 + reg (attn-verified layout)
#pragma unroll
  for (int ms = 0; ms < 2; ++ms)
#pragma unroll
    for (int nt = 0; nt < 4; ++nt)
#pragma unroll
      for (int rv = 0; rv < 4; ++rv) {
        int m = m0 + wid*32 + ms*16 + lgrp*4 + rv;
        int n = n0 + nt*16 + bcol;
        double val = (double)acch[ms][nt][rv] + (double)accl[ms][nt][rv] + (double)bias[n];
        int bb = m >> 11;          // /Tz
        int t = m & 2047;          // %Tz
        if (n < BNz) {
          int h = n >> 6, d = n & 63;
          q64[(((size_t)(bb*Hz + h))*Tz + t)*DHz + d] = val;
        } else if (n < 2*BNz) {
          int h = (n - BNz) >> 6, d = n & 63;
          size_t bh = (size_t)(bb*Hz + h);
          k64[(bh*Tz + t)*DHz + d] = val;
          kbf[(bh*Tz + t)*DHz + d] = f2bf((float)val);
        } else {
          int h = (n - 2*BNz) >> 6, d = n & 63;
          v32[(((size_t)(bb*Hz + h))*Tz + t)*DHz + d] = (float)val;
        }
      }
}

// ---- proj GEMM f32 (unchanged) --------------------------------------------
__global__ __launch_bounds__(256) void proj_gemm(
    const float* __restrict__ A, const float* __restrict__ W,
    const float* __restrict__ bias, float* __restrict__ out)
{
  __shared__ float As[16][68];
  __shared__ float Ws[16][68];
  const int tid = threadIdx.x;
  const int tx = tid & 15, ty = tid >> 4;
  const int m0 = blockIdx.y * 64, n0 = blockIdx.x * 64;
  const int lrow = tid >> 2, lkq = tid & 3;
  float acc[4][4] = {};
  const float* Aload = A + (size_t)(m0 + lrow) * Dz + lkq * 4;
  const float* Wload = W + (size_t)(n0 + lrow) * Dz + lkq * 4;
  for (int kt = 0; kt < Dz; kt += 16) {
    float4 a4 = *(const float4*)(Aload + kt);
    float4 w4 = *(const float4*)(Wload + kt);
    __syncthreads();
    As[lkq*4+0][lrow] = a4.x; As[lkq*4+1][lrow] = a4.y;
    As[lkq*4+2][lrow] = a4.z; As[lkq*4+3][lrow] = a4.w;
    Ws[lkq*4+0][lrow] = w4.x; Ws[lkq*4+1][lrow] = w4.y;
    Ws[lkq*4+2][lrow] = w4.z; Ws[lkq*4+3][lrow] = w4.w;
    __syncthreads();
#pragma unroll
    for (int k = 0; k < 16; ++k) {
      float4 av = *(const float4*)&As[k][ty*4];
      float4 wv = *(const float4*)&Ws[k][tx*4];
      float a_[4] = {av.x, av.y, av.z, av.w};
      float w_[4] = {wv.x, wv.y, wv.z, wv.w};
#pragma unroll
      for (int i = 0; i < 4; ++i)
#pragma unroll
        for (int j = 0; j < 4; ++j)
          acc[i][j] = fmaf(a_[i], w_[j], acc[i][j]);
    }
  }
#pragma unroll
  for (int i = 0; i < 4; ++i) {
    int m = m0 + ty*4 + i;
#pragma unroll
    for (int j = 0; j < 4; ++j) {
      int n = n0 + tx*4 + j;
      out[(size_t)m * Dz + n] = acc[i][j] + bias[n];
    }
  }
}

// ---- attention v7 (byte-identical to r12) ----------------------------------
__global__ __launch_bounds__(256) void attn_topk(
    const double* __restrict__ q64g, const double* __restrict__ k64g,
    const short* __restrict__ kbfg, const float* __restrict__ v32,
    float* __restrict__ y)
{
  __shared__ __align__(32) double q64_s[QBLK][DHz];
  __shared__ __align__(16) unsigned char ubuf[QBLK*CAND_MAX*6];
  __shared__ float cutlo[QBLK];
  __shared__ int candcnt[QBLK];

  unsigned* hist = (unsigned*)ubuf;
  float* candv = (float*)ubuf;
  unsigned short* candidx = (unsigned short*)(ubuf + QBLK*CAND_MAX*4);

  const int tid = threadIdx.x;
  const int bid0 = blockIdx.x;
  const int bh_f = (bid0 & 7) + 8 * (bid0 >> 10);
  const int qbf = (bid0 >> 3) & 127;
  const int h = bh_f & 15;
  const int bb = bh_f >> 4;
  const size_t bh = (size_t)(bb * Hz + h);
  const double* qg = q64g + (bh * Tz + (size_t)qbf * QBLK) * DHz;
  const double* kg64 = k64g + bh * Tz * DHz;
  const short* kb = kbfg + bh * Tz * DHz;
  const float* vg = v32 + bh * Tz * DHz;

  if (tid < QBLK) candcnt[tid] = 0;
  for (int i = tid; i < QBLK*256; i += 256) hist[i] = 0u;
  {
    int r = tid >> 4, d4 = (tid & 15) * 4;
    double4 qv = *(const double4*)&qg[r*DHz + d4];
    q64_s[r][d4+0] = qv.x; q64_s[r][d4+1] = qv.y;
    q64_s[r][d4+2] = qv.z; q64_s[r][d4+3] = qv.w;
  }
  __syncthreads();

  const int lane = tid & 63;
  const int wid = tid >> 6;
  const int bcol = lane & 15;
  const int lgrp = lane >> 4;
  bf16x8 aF0, aF1;
#pragma unroll
  for (int e = 0; e < 8; ++e) {
    aF0[e] = f2bf((float)q64_s[bcol][lgrp*8 + e]);
    aF1[e] = f2bf((float)q64_s[bcol][32 + lgrp*8 + e]);
  }
  const int t0base = wid * 512;

#pragma unroll 4
  for (int tt = 0; tt < 32; ++tt) {
    const short* kbp = kb + (size_t)(t0base + tt*16 + bcol) * DHz;
    bf16x8 b0 = *(const bf16x8*)(kbp + lgrp*8);
    bf16x8 b1 = *(const bf16x8*)(kbp + 32 + lgrp*8);
    f32x4 c = {0.f, 0.f, 0.f, 0.f};
    c = __builtin_amdgcn_mfma_f32_16x16x32_bf16(aF0, b0, c, 0, 0, 0);
    c = __builtin_amdgcn_mfma_f32_16x16x32_bf16(aF1, b1, c, 0, 0, 0);
#pragma unroll
    for (int j = 0; j < 4; ++j) {
      int bin = (int)((c[j] - SLO) * SBINR);
      bin = bin < 0 ? 0 : (bin > 255 ? 255 : bin);
      atomicAdd(&hist[(lgrp*4 + j)*256 + bin], 1u);
    }
  }
  __syncthreads();

  {
    int r = tid >> 4, i16 = tid & 15;
    int s = 0;
#pragma unroll
    for (int j = 0; j < 16; ++j) s += (int)hist[r*256 + i16*16 + j];
    int S = s;
#pragma unroll
    for (int off = 1; off < 16; off <<= 1) {
      int src = i16 + off;
      int v = __shfl(S, (lane & 48) | (src < 16 ? src : 15));
      S += (src < 16) ? v : 0;
    }
    unsigned long long blt = __ballot(S >= TOPKz);
    unsigned mask16 = (unsigned)((blt >> (lane & 48)) & 0xFFFFull);
    int istar = 31 - __builtin_clz(mask16);
    if (i16 == istar) {
      int cum = S - s;
      int b = istar * 16;
      for (int j = 15; j >= 0; --j) {
        cum += (int)hist[r*256 + istar*16 + j];
        if (cum >= TOPKz) { b = istar*16 + j; break; }
      }
      cutlo[r] = (SLO + (float)b * SBINW) - DELTA;
    }
  }
  __syncthreads();

#pragma unroll 4
  for (int tt = 0; tt < 32; ++tt) {
    const short* kbp = kb + (size_t)(t0base + tt*16 + bcol) * DHz;
    bf16x8 b0 = *(const bf16x8*)(kbp + lgrp*8);
    bf16x8 b1 = *(const bf16x8*)(kbp + 32 + lgrp*8);
    f32x4 c = {0.f, 0.f, 0.f, 0.f};
    c = __builtin_amdgcn_mfma_f32_16x16x32_bf16(aF0, b0, c, 0, 0, 0);
    c = __builtin_amdgcn_mfma_f32_16x16x32_bf16(aF1, b1, c, 0, 0, 0);
#pragma unroll
    for (int j = 0; j < 4; ++j) {
      int r = lgrp*4 + j;
      if (c[j] >= cutlo[r]) {
        int p = atomicAdd(&candcnt[r], 1);
        if (p < CAND_MAX) candidx[r*CAND_MAX + p] = (unsigned short)(t0base + tt*16 + bcol);
      }
    }
  }
  __syncthreads();

  {
    const int r = tid >> 4, i16 = tid & 15;
    int n = candcnt[r]; if (n > CAND_MAX) n = CAND_MAX;

    for (int i = i16; i < n; i += 16) {
      int col = (int)candidx[r*CAND_MAX + i];
      const double* kpd = kg64 + (size_t)col * DHz;
      double s = 0.0;
#pragma unroll
      for (int d = 0; d < DHz; d += 4) {
        double4 k4 = *(const double4*)(kpd + d);
        s = fma(q64_s[r][d+0], k4.x, s);
        s = fma(q64_s[r][d+1], k4.y, s);
        s = fma(q64_s[r][d+2], k4.z, s);
        s = fma(q64_s[r][d+3], k4.w, s);
      }
      candv[r*CAND_MAX + i] = (float)s;
    }

    float best = -3.0e38f, mx = -3.0e38f;
    for (int i = i16; i < n; i += 16) {
      float x = candv[r*CAND_MAX + i];
      mx = fmaxf(mx, x);
      int cnt = 0;
      for (int j = 0; j < n; ++j) cnt += (candv[r*CAND_MAX + j] >= x) ? 1 : 0;
      if (cnt >= TOPKz && x > best) best = x;
    }
#pragma unroll
    for (int m = 1; m < 16; m <<= 1) {
      best = fmaxf(best, __shfl_xor(best, m));
      mx   = fmaxf(mx,   __shfl_xor(mx, m));
    }
    const float T = best;

    int na = 0, nb = 0;
    for (int i = i16; i < n; i += 16) {
      float s = candv[r*CAND_MAX + i];
      if (s > T + BAND) na++;
      else if (s >= T - BAND) nb++;
    }
#pragma unroll
    for (int m = 1; m < 16; m <<= 1) {
      na += __shfl_xor(na, m);
      nb += __shfl_xor(nb, m);
    }
    const float wb = (float)(TOPKz - na) / (float)(nb > 0 ? nb : 1);

    float lsum = 0.f;
    for (int i = i16; i < n; i += 16) {
      float s = candv[r*CAND_MAX + i];
      float w = (s > T + BAND) ? 1.f : ((s >= T - BAND) ? wb : 0.f);
      float p = (w > 0.f) ? w * expf((s - mx) * 0.125f) : 0.f;
      candv[r*CAND_MAX + i] = p;
      lsum += p;
    }
#pragma unroll
    for (int m = 1; m < 16; m <<= 1) lsum += __shfl_xor(lsum, m);
    const float rd = 1.0f / lsum;

    const int dg = i16 * 4;
    float4 o = make_float4(0.f, 0.f, 0.f, 0.f);
    for (int i = 0; i < n; ++i) {
      float p = candv[r*CAND_MAX + i];
      if (p > 0.f) {
        int idx = (int)candidx[r*CAND_MAX + i];
        float4 vv = *(const float4*)&vg[(size_t)idx*DHz + dg];
        float pw = p * rd;
        o.x = fmaf(pw, vv.x, o.x);
        o.y = fmaf(pw, vv.y, o.y);
        o.z = fmaf(pw, vv.z, o.z);
        o.w = fmaf(pw, vv.w, o.w);
      }
    }
    float* yo = y + ((size_t)bb*Tz + (size_t)qbf*QBLK + r) * BNz + h*DHz + dg;
    *(float4*)yo = o;
  }
}

extern "C" void kernel_launch(void* const* d_in, const int* in_sizes, int n_in,
                              void* d_out, int out_size, void* d_ws, size_t ws_size,
                              hipStream_t stream)
{
  const float* x      = (const float*)d_in[0];
  const float* w_qkv  = (const float*)d_in[1];
  const float* b_qkv  = (const float*)d_in[2];
  const float* w_proj = (const float*)d_in[3];
  const float* b_proj = (const float*)d_in[4];
  float* out = (float*)d_out;

  const size_t E = (size_t)Bz * Hz * Tz * DHz;   // 4,194,304
  double* q64 = (double*)d_ws;                   // 32 MB
  double* k64 = q64 + E;                         // 32 MB
  short* kbf  = (short*)(k64 + E);               // 8 MB (bf16 K)
  float* v32  = (float*)(kbf + E);               // 16 MB
  float* y    = v32 + E;                         // 16 MB  (total 104 MB)

  qkv_gemm_split<<<dim3((3*BNz)/64, (Bz*Tz)/128), 256, 0, stream>>>(x, w_qkv, b_qkv, q64, k64, kbf, v32);
  attn_topk<<<Bz*Hz*(Tz/QBLK), 256, 0, stream>>>(q64, k64, kbf, v32, y);
  proj_gemm<<<dim3(Dz/64, (Bz*Tz)/64), 256, 0, stream>>>(y, w_proj, b_proj, out);
}

// Round 15
// 996.757 us; speedup vs baseline: 1.8400x; 1.0049x over previous
//
#include <hip/hip_runtime.h>
#include <hip/hip_bf16.h>
#include <math.h>

#define Bz 2
#define Tz 2048
#define Dz 1024
#define Hz 16
#define DHz 64
#define BNz 1024
#define TOPKz 64
#define QBLK 16
#define CAND_MAX 176
#define DELTA 0.35f   // >= 2x bf16-screen error bound (validated r6-r14)
#define BAND 8e-5f    // ambiguity half-band on RAW scores (verified r5-r14)
#define SLO  -20.0f
#define SBINW 0.15625f
#define SBINR 6.4f
#define LDSB 40       // bf16 LDS row stride: 80 B rows (16B-aligned, 2-way bank alias = free)

typedef __attribute__((ext_vector_type(8))) short bf16x8;
typedef __attribute__((ext_vector_type(4))) short s16x4;
typedef __attribute__((ext_vector_type(4))) float f32x4;

__device__ __forceinline__ short f2bf(float f) {     // RNE f32 -> bf16
  unsigned u = __float_as_uint(f);
  return (short)((u + 0x7FFFu + ((u >> 16) & 1u)) >> 16);
}
__device__ __forceinline__ float bf2f(short b) {
  return __uint_as_float(((unsigned)(unsigned short)b) << 16);
}
__device__ __forceinline__ unsigned f2s(float f) {   // order-preserving f32->u32
  unsigned u = __float_as_uint(f);
  return (u & 0x80000000u) ? ~u : (u | 0x80000000u);
}
__device__ __forceinline__ float s2f(unsigned u) {
  return __uint_as_float((u & 0x80000000u) ? (u & 0x7FFFFFFFu) : ~u);
}

// ---- QKV GEMM via bf16x3 split (byte-identical to r14) --------------------
__global__ __launch_bounds__(256) void qkv_gemm_split(
    const float* __restrict__ A, const float* __restrict__ W,
    const float* __restrict__ bias,
    double* __restrict__ q64, double* __restrict__ k64,
    short* __restrict__ kbf, float* __restrict__ v32)
{
  __shared__ __align__(16) short Ah[128][LDSB];
  __shared__ __align__(16) short Am[128][LDSB];
  __shared__ __align__(16) short Al[128][LDSB];
  __shared__ __align__(16) short Bh[64][LDSB];
  __shared__ __align__(16) short Bm[64][LDSB];
  __shared__ __align__(16) short Bl[64][LDSB];

  const int tid = threadIdx.x;
  const int lane = tid & 63, wid = tid >> 6;
  const int m0 = blockIdx.y * 128, n0 = blockIdx.x * 64;
  const int bcol = lane & 15, lgrp = lane >> 4;

  f32x4 acch[2][4], accl[2][4];
#pragma unroll
  for (int ms = 0; ms < 2; ++ms)
#pragma unroll
    for (int nt = 0; nt < 4; ++nt) {
      acch[ms][nt] = (f32x4){0.f, 0.f, 0.f, 0.f};
      accl[ms][nt] = (f32x4){0.f, 0.f, 0.f, 0.f};
    }

  const int arow = tid >> 1, ak = (tid & 1) * 16;
  const int brow = tid >> 2, bk = (tid & 3) * 8;
  const float* Ald = A + (size_t)(m0 + arow) * Dz + ak;
  const float* Wld = W + (size_t)(n0 + brow) * Dz + bk;

  for (int kt = 0; kt < Dz; kt += 32) {
    float4 a4[4], b4[2];
#pragma unroll
    for (int j = 0; j < 4; ++j) a4[j] = *(const float4*)(Ald + kt + 4*j);
#pragma unroll
    for (int j = 0; j < 2; ++j) b4[j] = *(const float4*)(Wld + kt + 4*j);
    __syncthreads();

#pragma unroll
    for (int j = 0; j < 4; ++j) {
      float vv[4] = {a4[j].x, a4[j].y, a4[j].z, a4[j].w};
      s16x4 h4, m4, l4;
#pragma unroll
      for (int e = 0; e < 4; ++e) {
        short hh = f2bf(vv[e]);
        float r1 = vv[e] - bf2f(hh);
        short mm = f2bf(r1);
        float r2 = r1 - bf2f(mm);
        h4[e] = hh; m4[e] = mm; l4[e] = f2bf(r2);
      }
      *(s16x4*)&Ah[arow][ak + 4*j] = h4;
      *(s16x4*)&Am[arow][ak + 4*j] = m4;
      *(s16x4*)&Al[arow][ak + 4*j] = l4;
    }
#pragma unroll
    for (int j = 0; j < 2; ++j) {
      float vv[4] = {b4[j].x, b4[j].y, b4[j].z, b4[j].w};
      s16x4 h4, m4, l4;
#pragma unroll
      for (int e = 0; e < 4; ++e) {
        short hh = f2bf(vv[e]);
        float r1 = vv[e] - bf2f(hh);
        short mm = f2bf(r1);
        float r2 = r1 - bf2f(mm);
        h4[e] = hh; m4[e] = mm; l4[e] = f2bf(r2);
      }
      *(s16x4*)&Bh[brow][bk + 4*j] = h4;
      *(s16x4*)&Bm[brow][bk + 4*j] = m4;
      *(s16x4*)&Bl[brow][bk + 4*j] = l4;
    }
    __syncthreads();

    bf16x8 ah[2], am[2], al[2];
#pragma unroll
    for (int ms = 0; ms < 2; ++ms) {
      int rr = wid*32 + ms*16 + bcol;
      ah[ms] = *(const bf16x8*)&Ah[rr][lgrp*8];
      am[ms] = *(const bf16x8*)&Am[rr][lgrp*8];
      al[ms] = *(const bf16x8*)&Al[rr][lgrp*8];
    }
#pragma unroll
    for (int nt = 0; nt < 4; ++nt) {
      int nr = nt*16 + bcol;
      bf16x8 bh = *(const bf16x8*)&Bh[nr][lgrp*8];
      bf16x8 bm = *(const bf16x8*)&Bm[nr][lgrp*8];
      bf16x8 bl = *(const bf16x8*)&Bl[nr][lgrp*8];
#pragma unroll
      for (int ms = 0; ms < 2; ++ms) {
        acch[ms][nt] = __builtin_amdgcn_mfma_f32_16x16x32_bf16(ah[ms], bh, acch[ms][nt], 0, 0, 0);
        accl[ms][nt] = __builtin_amdgcn_mfma_f32_16x16x32_bf16(ah[ms], bm, accl[ms][nt], 0, 0, 0);
        accl[ms][nt] = __builtin_amdgcn_mfma_f32_16x16x32_bf16(am[ms], bh, accl[ms][nt], 0, 0, 0);
        accl[ms][nt] = __builtin_amdgcn_mfma_f32_16x16x32_bf16(am[ms], bm, accl[ms][nt], 0, 0, 0);
        accl[ms][nt] = __builtin_amdgcn_mfma_f32_16x16x32_bf16(ah[ms], bl, accl[ms][nt], 0, 0, 0);
        accl[ms][nt] = __builtin_amdgcn_mfma_f32_16x16x32_bf16(al[ms], bh, accl[ms][nt], 0, 0, 0);
      }
    }
  }

#pragma unroll
  for (int ms = 0; ms < 2; ++ms)
#pragma unroll
    for (int nt = 0; nt < 4; ++nt)
#pragma unroll
      for (int rv = 0; rv < 4; ++rv) {
        int m = m0 + wid*32 + ms*16 + lgrp*4 + rv;
        int n = n0 + nt*16 + bcol;
        double val = (double)acch[ms][nt][rv] + (double)accl[ms][nt][rv] + (double)bias[n];
        int bb = m >> 11;
        int t = m & 2047;
        if (n < BNz) {
          int h = n >> 6, d = n & 63;
          q64[(((size_t)(bb*Hz + h))*Tz + t)*DHz + d] = val;
        } else if (n < 2*BNz) {
          int h = (n - BNz) >> 6, d = n & 63;
          size_t bh = (size_t)(bb*Hz + h);
          k64[(bh*Tz + t)*DHz + d] = val;
          kbf[(bh*Tz + t)*DHz + d] = f2bf((float)val);
        } else {
          int h = (n - 2*BNz) >> 6, d = n & 63;
          v32[(((size_t)(bb*Hz + h))*Tz + t)*DHz + d] = (float)val;
        }
      }
}

// ---- proj GEMM f32 (unchanged) --------------------------------------------
__global__ __launch_bounds__(256) void proj_gemm(
    const float* __restrict__ A, const float* __restrict__ W,
    const float* __restrict__ bias, float* __restrict__ out)
{
  __shared__ float As[16][68];
  __shared__ float Ws[16][68];
  const int tid = threadIdx.x;
  const int tx = tid & 15, ty = tid >> 4;
  const int m0 = blockIdx.y * 64, n0 = blockIdx.x * 64;
  const int lrow = tid >> 2, lkq = tid & 3;
  float acc[4][4] = {};
  const float* Aload = A + (size_t)(m0 + lrow) * Dz + lkq * 4;
  const float* Wload = W + (size_t)(n0 + lrow) * Dz + lkq * 4;
  for (int kt = 0; kt < Dz; kt += 16) {
    float4 a4 = *(const float4*)(Aload + kt);
    float4 w4 = *(const float4*)(Wload + kt);
    __syncthreads();
    As[lkq*4+0][lrow] = a4.x; As[lkq*4+1][lrow] = a4.y;
    As[lkq*4+2][lrow] = a4.z; As[lkq*4+3][lrow] = a4.w;
    Ws[lkq*4+0][lrow] = w4.x; Ws[lkq*4+1][lrow] = w4.y;
    Ws[lkq*4+2][lrow] = w4.z; Ws[lkq*4+3][lrow] = w4.w;
    __syncthreads();
#pragma unroll
    for (int k = 0; k < 16; ++k) {
      float4 av = *(const float4*)&As[k][ty*4];
      float4 wv = *(const float4*)&Ws[k][tx*4];
      float a_[4] = {av.x, av.y, av.z, av.w};
      float w_[4] = {wv.x, wv.y, wv.z, wv.w};
#pragma unroll
      for (int i = 0; i < 4; ++i)
#pragma unroll
        for (int j = 0; j < 4; ++j)
          acc[i][j] = fmaf(a_[i], w_[j], acc[i][j]);
    }
  }
#pragma unroll
  for (int i = 0; i < 4; ++i) {
    int m = m0 + ty*4 + i;
#pragma unroll
    for (int j = 0; j < 4; ++j) {
      int n = n0 + tx*4 + j;
      out[(size_t)m * Dz + n] = acc[i][j] + bias[n];
    }
  }
}

// ---- attention v8 = r12 structure + register-cached candidates +
//      EXACT rank-64 via order-preserving bit-space bisection (same T,
//      bit-identical output; ~10x fewer rank-phase issue slots).
__global__ __launch_bounds__(256) void attn_topk(
    const double* __restrict__ q64g, const double* __restrict__ k64g,
    const short* __restrict__ kbfg, const float* __restrict__ v32,
    float* __restrict__ y)
{
  __shared__ __align__(32) double q64_s[QBLK][DHz];
  __shared__ __align__(16) unsigned char ubuf[QBLK*CAND_MAX*6];
  __shared__ float cutlo[QBLK];
  __shared__ int candcnt[QBLK];

  unsigned* hist = (unsigned*)ubuf;
  float* candv = (float*)ubuf;
  unsigned short* candidx = (unsigned short*)(ubuf + QBLK*CAND_MAX*4);

  const int tid = threadIdx.x;
  const int bid0 = blockIdx.x;
  const int bh_f = (bid0 & 7) + 8 * (bid0 >> 10);
  const int qbf = (bid0 >> 3) & 127;
  const int h = bh_f & 15;
  const int bb = bh_f >> 4;
  const size_t bh = (size_t)(bb * Hz + h);
  const double* qg = q64g + (bh * Tz + (size_t)qbf * QBLK) * DHz;
  const double* kg64 = k64g + bh * Tz * DHz;
  const short* kb = kbfg + bh * Tz * DHz;
  const float* vg = v32 + bh * Tz * DHz;

  if (tid < QBLK) candcnt[tid] = 0;
  for (int i = tid; i < QBLK*256; i += 256) hist[i] = 0u;
  {
    int r = tid >> 4, d4 = (tid & 15) * 4;
    double4 qv = *(const double4*)&qg[r*DHz + d4];
    q64_s[r][d4+0] = qv.x; q64_s[r][d4+1] = qv.y;
    q64_s[r][d4+2] = qv.z; q64_s[r][d4+3] = qv.w;
  }
  __syncthreads();

  const int lane = tid & 63;
  const int wid = tid >> 6;
  const int bcol = lane & 15;
  const int lgrp = lane >> 4;
  bf16x8 aF0, aF1;
#pragma unroll
  for (int e = 0; e < 8; ++e) {
    aF0[e] = f2bf((float)q64_s[bcol][lgrp*8 + e]);
    aF1[e] = f2bf((float)q64_s[bcol][32 + lgrp*8 + e]);
  }
  const int t0base = wid * 512;

#pragma unroll 4
  for (int tt = 0; tt < 32; ++tt) {
    const short* kbp = kb + (size_t)(t0base + tt*16 + bcol) * DHz;
    bf16x8 b0 = *(const bf16x8*)(kbp + lgrp*8);
    bf16x8 b1 = *(const bf16x8*)(kbp + 32 + lgrp*8);
    f32x4 c = {0.f, 0.f, 0.f, 0.f};
    c = __builtin_amdgcn_mfma_f32_16x16x32_bf16(aF0, b0, c, 0, 0, 0);
    c = __builtin_amdgcn_mfma_f32_16x16x32_bf16(aF1, b1, c, 0, 0, 0);
#pragma unroll
    for (int j = 0; j < 4; ++j) {
      int bin = (int)((c[j] - SLO) * SBINR);
      bin = bin < 0 ? 0 : (bin > 255 ? 255 : bin);
      atomicAdd(&hist[(lgrp*4 + j)*256 + bin], 1u);
    }
  }
  __syncthreads();

  {
    int r = tid >> 4, i16 = tid & 15;
    int s = 0;
#pragma unroll
    for (int j = 0; j < 16; ++j) s += (int)hist[r*256 + i16*16 + j];
    int S = s;
#pragma unroll
    for (int off = 1; off < 16; off <<= 1) {
      int src = i16 + off;
      int v = __shfl(S, (lane & 48) | (src < 16 ? src : 15));
      S += (src < 16) ? v : 0;
    }
    unsigned long long blt = __ballot(S >= TOPKz);
    unsigned mask16 = (unsigned)((blt >> (lane & 48)) & 0xFFFFull);
    int istar = 31 - __builtin_clz(mask16);
    if (i16 == istar) {
      int cum = S - s;
      int b = istar * 16;
      for (int j = 15; j >= 0; --j) {
        cum += (int)hist[r*256 + istar*16 + j];
        if (cum >= TOPKz) { b = istar*16 + j; break; }
      }
      cutlo[r] = (SLO + (float)b * SBINW) - DELTA;
    }
  }
  __syncthreads();

#pragma unroll 4
  for (int tt = 0; tt < 32; ++tt) {
    const short* kbp = kb + (size_t)(t0base + tt*16 + bcol) * DHz;
    bf16x8 b0 = *(const bf16x8*)(kbp + lgrp*8);
    bf16x8 b1 = *(const bf16x8*)(kbp + 32 + lgrp*8);
    f32x4 c = {0.f, 0.f, 0.f, 0.f};
    c = __builtin_amdgcn_mfma_f32_16x16x32_bf16(aF0, b0, c, 0, 0, 0);
    c = __builtin_amdgcn_mfma_f32_16x16x32_bf16(aF1, b1, c, 0, 0, 0);
#pragma unroll
    for (int j = 0; j < 4; ++j) {
      int r = lgrp*4 + j;
      if (c[j] >= cutlo[r]) {
        int p = atomicAdd(&candcnt[r], 1);
        if (p < CAND_MAX) candidx[r*CAND_MAX + p] = (unsigned short)(t0base + tt*16 + bcol);
      }
    }
  }
  __syncthreads();

  {
    const int r = tid >> 4, i16 = tid & 15;
    int n = candcnt[r]; if (n > CAND_MAX) n = CAND_MAX;

    // f64 rescore, thread-per-candidate (unchanged)
    for (int i = i16; i < n; i += 16) {
      int col = (int)candidx[r*CAND_MAX + i];
      const double* kpd = kg64 + (size_t)col * DHz;
      double s = 0.0;
#pragma unroll
      for (int d = 0; d < DHz; d += 4) {
        double4 k4 = *(const double4*)(kpd + d);
        s = fma(q64_s[r][d+0], k4.x, s);
        s = fma(q64_s[r][d+1], k4.y, s);
        s = fma(q64_s[r][d+2], k4.z, s);
        s = fma(q64_s[r][d+3], k4.w, s);
      }
      candv[r*CAND_MAX + i] = (float)s;
    }

    // cache own candidates in registers (<= CAND_MAX/16 = 11) + row max
    float myv[11];
    float mx = -3.0e38f;
#pragma unroll
    for (int j = 0; j < 11; ++j) {
      int i = i16 + j*16;
      float x = (i < n) ? candv[r*CAND_MAX + i] : -3.0e38f;
      myv[j] = x;
      mx = fmaxf(mx, x);
    }
#pragma unroll
    for (int m = 1; m < 16; m <<= 1) mx = fmaxf(mx, __shfl_xor(mx, m));

    // EXACT rank-64 threshold via bit-space bisection:
    // T = largest float with count(>=T) >= 64. Invariants:
    // count(>=s2f(lo))>=64 (all n>=64 candidates >= cutlo), count(>=s2f(hi))==0.
    unsigned lo_u = f2s(cutlo[r]);
    unsigned hi_u = f2s(mx) + 1u;
    while (hi_u - lo_u > 1u) {
      unsigned mid = lo_u + ((hi_u - lo_u) >> 1);
      float tv = s2f(mid);
      int cnt = 0;
#pragma unroll
      for (int j = 0; j < 11; ++j) cnt += (myv[j] >= tv) ? 1 : 0;
#pragma unroll
      for (int m = 1; m < 16; m <<= 1) cnt += __shfl_xor(cnt, m);
      if (cnt >= TOPKz) lo_u = mid; else hi_u = mid;
    }
    const float T = s2f(lo_u);

    // ambiguity band stats from registers
    int na = 0, nb = 0;
#pragma unroll
    for (int j = 0; j < 11; ++j) {
      float s = myv[j];
      if (s > T + BAND) na++;
      else if (s >= T - BAND) nb++;
    }
#pragma unroll
    for (int m = 1; m < 16; m <<= 1) {
      na += __shfl_xor(na, m);
      nb += __shfl_xor(nb, m);
    }
    const float wb = (float)(TOPKz - na) / (float)(nb > 0 ? nb : 1);

    // softmax numerators (registers -> candv in place) + denom via shfl
    float lsum = 0.f;
#pragma unroll
    for (int j = 0; j < 11; ++j) {
      int i = i16 + j*16;
      if (i < n) {
        float s = myv[j];
        float w = (s > T + BAND) ? 1.f : ((s >= T - BAND) ? wb : 0.f);
        float p = (w > 0.f) ? w * expf((s - mx) * 0.125f) : 0.f;
        candv[r*CAND_MAX + i] = p;
        lsum += p;
      }
    }
#pragma unroll
    for (int m = 1; m < 16; m <<= 1) lsum += __shfl_xor(lsum, m);
    const float rd = 1.0f / lsum;

    // sparse AV
    const int dg = i16 * 4;
    float4 o = make_float4(0.f, 0.f, 0.f, 0.f);
    for (int i = 0; i < n; ++i) {
      float p = candv[r*CAND_MAX + i];
      if (p > 0.f) {
        int idx = (int)candidx[r*CAND_MAX + i];
        float4 vv = *(const float4*)&vg[(size_t)idx*DHz + dg];
        float pw = p * rd;
        o.x = fmaf(pw, vv.x, o.x);
        o.y = fmaf(pw, vv.y, o.y);
        o.z = fmaf(pw, vv.z, o.z);
        o.w = fmaf(pw, vv.w, o.w);
      }
    }
    float* yo = y + ((size_t)bb*Tz + (size_t)qbf*QBLK + r) * BNz + h*DHz + dg;
    *(float4*)yo = o;
  }
}

extern "C" void kernel_launch(void* const* d_in, const int* in_sizes, int n_in,
                              void* d_out, int out_size, void* d_ws, size_t ws_size,
                              hipStream_t stream)
{
  const float* x      = (const float*)d_in[0];
  const float* w_qkv  = (const float*)d_in[1];
  const float* b_qkv  = (const float*)d_in[2];
  const float* w_proj = (const float*)d_in[3];
  const float* b_proj = (const float*)d_in[4];
  float* out = (float*)d_out;

  const size_t E = (size_t)Bz * Hz * Tz * DHz;   // 4,194,304
  double* q64 = (double*)d_ws;                   // 32 MB
  double* k64 = q64 + E;                         // 32 MB
  short* kbf  = (short*)(k64 + E);               // 8 MB (bf16 K)
  float* v32  = (float*)(kbf + E);               // 16 MB
  float* y    = v32 + E;                         // 16 MB  (total 104 MB)

  qkv_gemm_split<<<dim3((3*BNz)/64, (Bz*Tz)/128), 256, 0, stream>>>(x, w_qkv, b_qkv, q64, k64, kbf, v32);
  attn_topk<<<Bz*Hz*(Tz/QBLK), 256, 0, stream>>>(q64, k64, kbf, v32, y);
  proj_gemm<<<dim3(Dz/64, (Bz*Tz)/64), 256, 0, stream>>>(y, w_proj, b_proj, out);
}

// Round 16
// 877.182 us; speedup vs baseline: 2.0908x; 1.1363x over previous
//
#include <hip/hip_runtime.h>
#include <hip/hip_bf16.h>
#include <math.h>

#define Bz 2
#define Tz 2048
#define Dz 1024
#define Hz 16
#define DHz 64
#define BNz 1024
#define TOPKz 64
#define QBLK 16
#define CAND_MAX 176
#define BAND 8e-5f    // ambiguity half-band on RAW scores (verified r5-r15)
#define SLO  -20.0f
#define SBINW 0.15625f
#define SBINR 6.4f
#define LDSB 40

typedef __attribute__((ext_vector_type(8))) short bf16x8;
typedef __attribute__((ext_vector_type(4))) short s16x4;
typedef __attribute__((ext_vector_type(4))) float f32x4;

__device__ __forceinline__ short f2bf(float f) {     // RNE f32 -> bf16
  unsigned u = __float_as_uint(f);
  return (short)((u + 0x7FFFu + ((u >> 16) & 1u)) >> 16);
}
__device__ __forceinline__ float bf2f(short b) {
  return __uint_as_float(((unsigned)(unsigned short)b) << 16);
}
__device__ __forceinline__ unsigned f2s(float f) {   // order-preserving f32->u32
  unsigned u = __float_as_uint(f);
  return (u & 0x80000000u) ? ~u : (u | 0x80000000u);
}
__device__ __forceinline__ float s2f(unsigned u) {
  return __uint_as_float((u & 0x80000000u) ? (u & 0x7FFFFFFFu) : ~u);
}

// ---- QKV GEMM via bf16x3 split (byte-identical to r14/r15) ----------------
__global__ __launch_bounds__(256) void qkv_gemm_split(
    const float* __restrict__ A, const float* __restrict__ W,
    const float* __restrict__ bias,
    double* __restrict__ q64, double* __restrict__ k64,
    short* __restrict__ kbf, float* __restrict__ v32)
{
  __shared__ __align__(16) short Ah[128][LDSB];
  __shared__ __align__(16) short Am[128][LDSB];
  __shared__ __align__(16) short Al[128][LDSB];
  __shared__ __align__(16) short Bh[64][LDSB];
  __shared__ __align__(16) short Bm[64][LDSB];
  __shared__ __align__(16) short Bl[64][LDSB];

  const int tid = threadIdx.x;
  const int lane = tid & 63, wid = tid >> 6;
  const int m0 = blockIdx.y * 128, n0 = blockIdx.x * 64;
  const int bcol = lane & 15, lgrp = lane >> 4;

  f32x4 acch[2][4], accl[2][4];
#pragma unroll
  for (int ms = 0; ms < 2; ++ms)
#pragma unroll
    for (int nt = 0; nt < 4; ++nt) {
      acch[ms][nt] = (f32x4){0.f, 0.f, 0.f, 0.f};
      accl[ms][nt] = (f32x4){0.f, 0.f, 0.f, 0.f};
    }

  const int arow = tid >> 1, ak = (tid & 1) * 16;
  const int brow = tid >> 2, bk = (tid & 3) * 8;
  const float* Ald = A + (size_t)(m0 + arow) * Dz + ak;
  const float* Wld = W + (size_t)(n0 + brow) * Dz + bk;

  for (int kt = 0; kt < Dz; kt += 32) {
    float4 a4[4], b4[2];
#pragma unroll
    for (int j = 0; j < 4; ++j) a4[j] = *(const float4*)(Ald + kt + 4*j);
#pragma unroll
    for (int j = 0; j < 2; ++j) b4[j] = *(const float4*)(Wld + kt + 4*j);
    __syncthreads();

#pragma unroll
    for (int j = 0; j < 4; ++j) {
      float vv[4] = {a4[j].x, a4[j].y, a4[j].z, a4[j].w};
      s16x4 h4, m4, l4;
#pragma unroll
      for (int e = 0; e < 4; ++e) {
        short hh = f2bf(vv[e]);
        float r1 = vv[e] - bf2f(hh);
        short mm = f2bf(r1);
        float r2 = r1 - bf2f(mm);
        h4[e] = hh; m4[e] = mm; l4[e] = f2bf(r2);
      }
      *(s16x4*)&Ah[arow][ak + 4*j] = h4;
      *(s16x4*)&Am[arow][ak + 4*j] = m4;
      *(s16x4*)&Al[arow][ak + 4*j] = l4;
    }
#pragma unroll
    for (int j = 0; j < 2; ++j) {
      float vv[4] = {b4[j].x, b4[j].y, b4[j].z, b4[j].w};
      s16x4 h4, m4, l4;
#pragma unroll
      for (int e = 0; e < 4; ++e) {
        short hh = f2bf(vv[e]);
        float r1 = vv[e] - bf2f(hh);
        short mm = f2bf(r1);
        float r2 = r1 - bf2f(mm);
        h4[e] = hh; m4[e] = mm; l4[e] = f2bf(r2);
      }
      *(s16x4*)&Bh[brow][bk + 4*j] = h4;
      *(s16x4*)&Bm[brow][bk + 4*j] = m4;
      *(s16x4*)&Bl[brow][bk + 4*j] = l4;
    }
    __syncthreads();

    bf16x8 ah[2], am[2], al[2];
#pragma unroll
    for (int ms = 0; ms < 2; ++ms) {
      int rr = wid*32 + ms*16 + bcol;
      ah[ms] = *(const bf16x8*)&Ah[rr][lgrp*8];
      am[ms] = *(const bf16x8*)&Am[rr][lgrp*8];
      al[ms] = *(const bf16x8*)&Al[rr][lgrp*8];
    }
#pragma unroll
    for (int nt = 0; nt < 4; ++nt) {
      int nr = nt*16 + bcol;
      bf16x8 bh = *(const bf16x8*)&Bh[nr][lgrp*8];
      bf16x8 bm = *(const bf16x8*)&Bm[nr][lgrp*8];
      bf16x8 bl = *(const bf16x8*)&Bl[nr][lgrp*8];
#pragma unroll
      for (int ms = 0; ms < 2; ++ms) {
        acch[ms][nt] = __builtin_amdgcn_mfma_f32_16x16x32_bf16(ah[ms], bh, acch[ms][nt], 0, 0, 0);
        accl[ms][nt] = __builtin_amdgcn_mfma_f32_16x16x32_bf16(ah[ms], bm, accl[ms][nt], 0, 0, 0);
        accl[ms][nt] = __builtin_amdgcn_mfma_f32_16x16x32_bf16(am[ms], bh, accl[ms][nt], 0, 0, 0);
        accl[ms][nt] = __builtin_amdgcn_mfma_f32_16x16x32_bf16(am[ms], bm, accl[ms][nt], 0, 0, 0);
        accl[ms][nt] = __builtin_amdgcn_mfma_f32_16x16x32_bf16(ah[ms], bl, accl[ms][nt], 0, 0, 0);
        accl[ms][nt] = __builtin_amdgcn_mfma_f32_16x16x32_bf16(al[ms], bh, accl[ms][nt], 0, 0, 0);
      }
    }
  }

#pragma unroll
  for (int ms = 0; ms < 2; ++ms)
#pragma unroll
    for (int nt = 0; nt < 4; ++nt)
#pragma unroll
      for (int rv = 0; rv < 4; ++rv) {
        int m = m0 + wid*32 + ms*16 + lgrp*4 + rv;
        int n = n0 + nt*16 + bcol;
        double val = (double)acch[ms][nt][rv] + (double)accl[ms][nt][rv] + (double)bias[n];
        int bb = m >> 11;
        int t = m & 2047;
        if (n < BNz) {
          int h = n >> 6, d = n & 63;
          q64[(((size_t)(bb*Hz + h))*Tz + t)*DHz + d] = val;
        } else if (n < 2*BNz) {
          int h = (n - BNz) >> 6, d = n & 63;
          size_t bh = (size_t)(bb*Hz + h);
          k64[(bh*Tz + t)*DHz + d] = val;
          kbf[(bh*Tz + t)*DHz + d] = f2bf((float)val);
        } else {
          int h = (n - 2*BNz) >> 6, d = n & 63;
          v32[(((size_t)(bb*Hz + h))*Tz + t)*DHz + d] = (float)val;
        }
      }
}

// ---- proj GEMM f32 (unchanged) --------------------------------------------
__global__ __launch_bounds__(256) void proj_gemm(
    const float* __restrict__ A, const float* __restrict__ W,
    const float* __restrict__ bias, float* __restrict__ out)
{
  __shared__ float As[16][68];
  __shared__ float Ws[16][68];
  const int tid = threadIdx.x;
  const int tx = tid & 15, ty = tid >> 4;
  const int m0 = blockIdx.y * 64, n0 = blockIdx.x * 64;
  const int lrow = tid >> 2, lkq = tid & 3;
  float acc[4][4] = {};
  const float* Aload = A + (size_t)(m0 + lrow) * Dz + lkq * 4;
  const float* Wload = W + (size_t)(n0 + lrow) * Dz + lkq * 4;
  for (int kt = 0; kt < Dz; kt += 16) {
    float4 a4 = *(const float4*)(Aload + kt);
    float4 w4 = *(const float4*)(Wload + kt);
    __syncthreads();
    As[lkq*4+0][lrow] = a4.x; As[lkq*4+1][lrow] = a4.y;
    As[lkq*4+2][lrow] = a4.z; As[lkq*4+3][lrow] = a4.w;
    Ws[lkq*4+0][lrow] = w4.x; Ws[lkq*4+1][lrow] = w4.y;
    Ws[lkq*4+2][lrow] = w4.z; Ws[lkq*4+3][lrow] = w4.w;
    __syncthreads();
#pragma unroll
    for (int k = 0; k < 16; ++k) {
      float4 av = *(const float4*)&As[k][ty*4];
      float4 wv = *(const float4*)&Ws[k][tx*4];
      float a_[4] = {av.x, av.y, av.z, av.w};
      float w_[4] = {wv.x, wv.y, wv.z, wv.w};
#pragma unroll
      for (int i = 0; i < 4; ++i)
#pragma unroll
        for (int j = 0; j < 4; ++j)
          acc[i][j] = fmaf(a_[i], w_[j], acc[i][j]);
    }
  }
#pragma unroll
  for (int i = 0; i < 4; ++i) {
    int m = m0 + ty*4 + i;
#pragma unroll
    for (int j = 0; j < 4; ++j) {
      int n = n0 + tx*4 + j;
      out[(size_t)m * Dz + n] = acc[i][j] + bias[n];
    }
  }
}

// ---- attention v9: SINGLE MFMA pass with register-cached u8 bins;
//      collect from registers (2nd kbf pass deleted). bin >= bstar-1
//      keeps the candidate superset guarantee (1 bin = 0.156 >= 2*err+BAND,
//      err <= 0.077 = 15 sigma of bf16 screen noise). Selection math
//      (f64 rescore, bit-bisect T, band, softmax) identical to r15.
__global__ __launch_bounds__(256) void attn_topk(
    const double* __restrict__ q64g, const double* __restrict__ k64g,
    const short* __restrict__ kbfg, const float* __restrict__ v32,
    float* __restrict__ y)
{
  __shared__ __align__(32) double q64_s[QBLK][DHz];
  __shared__ __align__(16) unsigned char ubuf[QBLK*CAND_MAX*6];
  __shared__ int bstar_s[QBLK];
  __shared__ int candcnt[QBLK];

  unsigned* hist = (unsigned*)ubuf;
  float* candv = (float*)ubuf;
  unsigned short* candidx = (unsigned short*)(ubuf + QBLK*CAND_MAX*4);

  const int tid = threadIdx.x;
  const int bid0 = blockIdx.x;
  const int bh_f = (bid0 & 7) + 8 * (bid0 >> 10);
  const int qbf = (bid0 >> 3) & 127;
  const int h = bh_f & 15;
  const int bb = bh_f >> 4;
  const size_t bh = (size_t)(bb * Hz + h);
  const double* qg = q64g + (bh * Tz + (size_t)qbf * QBLK) * DHz;
  const double* kg64 = k64g + bh * Tz * DHz;
  const short* kb = kbfg + bh * Tz * DHz;
  const float* vg = v32 + bh * Tz * DHz;

  if (tid < QBLK) candcnt[tid] = 0;
  for (int i = tid; i < QBLK*256; i += 256) hist[i] = 0u;
  {
    int r = tid >> 4, d4 = (tid & 15) * 4;
    double4 qv = *(const double4*)&qg[r*DHz + d4];
    q64_s[r][d4+0] = qv.x; q64_s[r][d4+1] = qv.y;
    q64_s[r][d4+2] = qv.z; q64_s[r][d4+3] = qv.w;
  }
  __syncthreads();                                    // barrier 1

  const int lane = tid & 63;
  const int wid = tid >> 6;
  const int bcol = lane & 15;
  const int lgrp = lane >> 4;
  bf16x8 aF0, aF1;
#pragma unroll
  for (int e = 0; e < 8; ++e) {
    aF0[e] = f2bf((float)q64_s[bcol][lgrp*8 + e]);
    aF1[e] = f2bf((float)q64_s[bcol][32 + lgrp*8 + e]);
  }
  const int t0base = wid * 512;

  // ---- single MFMA pass: hist + pack bins into 32 registers ----
  unsigned binreg[32];
#pragma unroll 4
  for (int tt = 0; tt < 32; ++tt) {
    const short* kbp = kb + (size_t)(t0base + tt*16 + bcol) * DHz;
    bf16x8 b0 = *(const bf16x8*)(kbp + lgrp*8);
    bf16x8 b1 = *(const bf16x8*)(kbp + 32 + lgrp*8);
    f32x4 c = {0.f, 0.f, 0.f, 0.f};
    c = __builtin_amdgcn_mfma_f32_16x16x32_bf16(aF0, b0, c, 0, 0, 0);
    c = __builtin_amdgcn_mfma_f32_16x16x32_bf16(aF1, b1, c, 0, 0, 0);
    unsigned bw = 0u;
#pragma unroll
    for (int j = 0; j < 4; ++j) {
      int bin = (int)((c[j] - SLO) * SBINR);
      bin = bin < 0 ? 0 : (bin > 255 ? 255 : bin);
      atomicAdd(&hist[(lgrp*4 + j)*256 + bin], 1u);
      bw |= ((unsigned)bin) << (8*j);
    }
    binreg[tt] = bw;
  }
  __syncthreads();                                    // barrier 2

  // ---- parallel cut: 16-lane suffix scan + ballot -> crossing bin ----
  {
    int r = tid >> 4, i16 = tid & 15;
    int s = 0;
#pragma unroll
    for (int j = 0; j < 16; ++j) s += (int)hist[r*256 + i16*16 + j];
    int S = s;
#pragma unroll
    for (int off = 1; off < 16; off <<= 1) {
      int src = i16 + off;
      int v = __shfl(S, (lane & 48) | (src < 16 ? src : 15));
      S += (src < 16) ? v : 0;
    }
    unsigned long long blt = __ballot(S >= TOPKz);
    unsigned mask16 = (unsigned)((blt >> (lane & 48)) & 0xFFFFull);
    int istar = 31 - __builtin_clz(mask16);
    if (i16 == istar) {
      int cum = S - s;
      int b = istar * 16;
      for (int j = 15; j >= 0; --j) {
        cum += (int)hist[r*256 + istar*16 + j];
        if (cum >= TOPKz) { b = istar*16 + j; break; }
      }
      bstar_s[r] = b;
    }
  }
  __syncthreads();                                    // barrier 3 (hist dead)

  // ---- collect from REGISTERS: bin >= bstar-1 (no loads, no MFMA) ----
  {
    int bc[4];
#pragma unroll
    for (int j = 0; j < 4; ++j) {
      int b = bstar_s[lgrp*4 + j] - 1;
      bc[j] = b < 0 ? 0 : b;
    }
#pragma unroll
    for (int tt = 0; tt < 32; ++tt) {
      unsigned bw = binreg[tt];
#pragma unroll
      for (int j = 0; j < 4; ++j) {
        int bin = (int)((bw >> (8*j)) & 255u);
        if (bin >= bc[j]) {
          int r = lgrp*4 + j;
          int p = atomicAdd(&candcnt[r], 1);
          if (p < CAND_MAX) candidx[r*CAND_MAX + p] = (unsigned short)(t0base + tt*16 + bcol);
        }
      }
    }
  }
  __syncthreads();                                    // barrier 4 (last)

  // ==== group-local: f64 rescore / exact rank-64 / band / softmax / AV ====
  {
    const int r = tid >> 4, i16 = tid & 15;
    int n = candcnt[r]; if (n > CAND_MAX) n = CAND_MAX;

    for (int i = i16; i < n; i += 16) {
      int col = (int)candidx[r*CAND_MAX + i];
      const double* kpd = kg64 + (size_t)col * DHz;
      double s = 0.0;
#pragma unroll
      for (int d = 0; d < DHz; d += 4) {
        double4 k4 = *(const double4*)(kpd + d);
        s = fma(q64_s[r][d+0], k4.x, s);
        s = fma(q64_s[r][d+1], k4.y, s);
        s = fma(q64_s[r][d+2], k4.z, s);
        s = fma(q64_s[r][d+3], k4.w, s);
      }
      candv[r*CAND_MAX + i] = (float)s;
    }

    float myv[11];
    float mx = -3.0e38f;
#pragma unroll
    for (int j = 0; j < 11; ++j) {
      int i = i16 + j*16;
      float x = (i < n) ? candv[r*CAND_MAX + i] : -3.0e38f;
      myv[j] = x;
      mx = fmaxf(mx, x);
    }
#pragma unroll
    for (int m = 1; m < 16; m <<= 1) mx = fmaxf(mx, __shfl_xor(mx, m));

    // EXACT rank-64 via bit-space bisection. lo seed: lowest candidate
    // value present (bstar-1 lower edge minus margin) -> use min over
    // candidates: all candidates >= s2f(lo) trivially if lo = min - 1ulp.
    float mn = 3.0e38f;
#pragma unroll
    for (int j = 0; j < 11; ++j) {
      int i = i16 + j*16;
      if (i < n) mn = fminf(mn, myv[j]);
    }
#pragma unroll
    for (int m = 1; m < 16; m <<= 1) mn = fminf(mn, __shfl_xor(mn, m));
    unsigned lo_u = f2s(mn);            // count(>= mn) = n >= 64
    unsigned hi_u = f2s(mx) + 1u;       // count == 0
    while (hi_u - lo_u > 1u) {
      unsigned mid = lo_u + ((hi_u - lo_u) >> 1);
      float tv = s2f(mid);
      int cnt = 0;
#pragma unroll
      for (int j = 0; j < 11; ++j) cnt += (myv[j] >= tv) ? 1 : 0;
#pragma unroll
      for (int m = 1; m < 16; m <<= 1) cnt += __shfl_xor(cnt, m);
      if (cnt >= TOPKz) lo_u = mid; else hi_u = mid;
    }
    const float T = s2f(lo_u);

    int na = 0, nb = 0;
#pragma unroll
    for (int j = 0; j < 11; ++j) {
      float s = myv[j];
      if (s > T + BAND) na++;
      else if (s >= T - BAND) nb++;
    }
#pragma unroll
    for (int m = 1; m < 16; m <<= 1) {
      na += __shfl_xor(na, m);
      nb += __shfl_xor(nb, m);
    }
    const float wb = (float)(TOPKz - na) / (float)(nb > 0 ? nb : 1);

    float lsum = 0.f;
#pragma unroll
    for (int j = 0; j < 11; ++j) {
      int i = i16 + j*16;
      if (i < n) {
        float s = myv[j];
        float w = (s > T + BAND) ? 1.f : ((s >= T - BAND) ? wb : 0.f);
        float p = (w > 0.f) ? w * expf((s - mx) * 0.125f) : 0.f;
        candv[r*CAND_MAX + i] = p;
        lsum += p;
      }
    }
#pragma unroll
    for (int m = 1; m < 16; m <<= 1) lsum += __shfl_xor(lsum, m);
    const float rd = 1.0f / lsum;

    const int dg = i16 * 4;
    float4 o = make_float4(0.f, 0.f, 0.f, 0.f);
    for (int i = 0; i < n; ++i) {
      float p = candv[r*CAND_MAX + i];
      if (p > 0.f) {
        int idx = (int)candidx[r*CAND_MAX + i];
        float4 vv = *(const float4*)&vg[(size_t)idx*DHz + dg];
        float pw = p * rd;
        o.x = fmaf(pw, vv.x, o.x);
        o.y = fmaf(pw, vv.y, o.y);
        o.z = fmaf(pw, vv.z, o.z);
        o.w = fmaf(pw, vv.w, o.w);
      }
    }
    float* yo = y + ((size_t)bb*Tz + (size_t)qbf*QBLK + r) * BNz + h*DHz + dg;
    *(float4*)yo = o;
  }
}

extern "C" void kernel_launch(void* const* d_in, const int* in_sizes, int n_in,
                              void* d_out, int out_size, void* d_ws, size_t ws_size,
                              hipStream_t stream)
{
  const float* x      = (const float*)d_in[0];
  const float* w_qkv  = (const float*)d_in[1];
  const float* b_qkv  = (const float*)d_in[2];
  const float* w_proj = (const float*)d_in[3];
  const float* b_proj = (const float*)d_in[4];
  float* out = (float*)d_out;

  const size_t E = (size_t)Bz * Hz * Tz * DHz;   // 4,194,304
  double* q64 = (double*)d_ws;                   // 32 MB
  double* k64 = q64 + E;                         // 32 MB
  short* kbf  = (short*)(k64 + E);               // 8 MB (bf16 K)
  float* v32  = (float*)(kbf + E);               // 16 MB
  float* y    = v32 + E;                         // 16 MB  (total 104 MB)

  qkv_gemm_split<<<dim3((3*BNz)/64, (Bz*Tz)/128), 256, 0, stream>>>(x, w_qkv, b_qkv, q64, k64, kbf, v32);
  attn_topk<<<Bz*Hz*(Tz/QBLK), 256, 0, stream>>>(q64, k64, kbf, v32, y);
  proj_gemm<<<dim3(Dz/64, (Bz*Tz)/64), 256, 0, stream>>>(y, w_proj, b_proj, out);
}

// Round 17
// 735.188 us; speedup vs baseline: 2.4947x; 1.1931x over previous
//
#include <hip/hip_runtime.h>
#include <hip/hip_bf16.h>
#include <math.h>

#define Bz 2
#define Tz 2048
#define Dz 1024
#define Hz 16
#define DHz 64
#define BNz 1024
#define TOPKz 64
#define QBLK 16
#define CAND_MAX 176
#define BAND 8e-5f    // ambiguity half-band on RAW scores (verified r5-r16)
#define SLO  -20.0f
#define SBINW 0.15625f
#define SBINR 6.4f
#define LDSB 40

typedef __attribute__((ext_vector_type(8))) short bf16x8;
typedef __attribute__((ext_vector_type(4))) short s16x4;
typedef __attribute__((ext_vector_type(4))) float f32x4;

__device__ __forceinline__ short f2bf(float f) {     // RNE f32 -> bf16
  unsigned u = __float_as_uint(f);
  return (short)((u + 0x7FFFu + ((u >> 16) & 1u)) >> 16);
}
__device__ __forceinline__ float bf2f(short b) {
  return __uint_as_float(((unsigned)(unsigned short)b) << 16);
}
__device__ __forceinline__ unsigned f2s(float f) {   // order-preserving f32->u32
  unsigned u = __float_as_uint(f);
  return (u & 0x80000000u) ? ~u : (u | 0x80000000u);
}
__device__ __forceinline__ float s2f(unsigned u) {
  return __uint_as_float((u & 0x80000000u) ? (u & 0x7FFFFFFFu) : ~u);
}

// ---- QKV GEMM via bf16x3 split; q,k now stored f32 (rescore reads f32,
//      accumulates f64 — storage quantization adds ~1.2e-6 score error,
//      << BAND slack). Structure identical to r14-r16.
__global__ __launch_bounds__(256) void qkv_gemm_split(
    const float* __restrict__ A, const float* __restrict__ W,
    const float* __restrict__ bias,
    float* __restrict__ q32, float* __restrict__ k32,
    short* __restrict__ kbf, float* __restrict__ v32)
{
  __shared__ __align__(16) short Ah[128][LDSB];
  __shared__ __align__(16) short Am[128][LDSB];
  __shared__ __align__(16) short Al[128][LDSB];
  __shared__ __align__(16) short Bh[64][LDSB];
  __shared__ __align__(16) short Bm[64][LDSB];
  __shared__ __align__(16) short Bl[64][LDSB];

  const int tid = threadIdx.x;
  const int lane = tid & 63, wid = tid >> 6;
  const int m0 = blockIdx.y * 128, n0 = blockIdx.x * 64;
  const int bcol = lane & 15, lgrp = lane >> 4;

  f32x4 acch[2][4], accl[2][4];
#pragma unroll
  for (int ms = 0; ms < 2; ++ms)
#pragma unroll
    for (int nt = 0; nt < 4; ++nt) {
      acch[ms][nt] = (f32x4){0.f, 0.f, 0.f, 0.f};
      accl[ms][nt] = (f32x4){0.f, 0.f, 0.f, 0.f};
    }

  const int arow = tid >> 1, ak = (tid & 1) * 16;
  const int brow = tid >> 2, bk = (tid & 3) * 8;
  const float* Ald = A + (size_t)(m0 + arow) * Dz + ak;
  const float* Wld = W + (size_t)(n0 + brow) * Dz + bk;

  for (int kt = 0; kt < Dz; kt += 32) {
    float4 a4[4], b4[2];
#pragma unroll
    for (int j = 0; j < 4; ++j) a4[j] = *(const float4*)(Ald + kt + 4*j);
#pragma unroll
    for (int j = 0; j < 2; ++j) b4[j] = *(const float4*)(Wld + kt + 4*j);
    __syncthreads();

#pragma unroll
    for (int j = 0; j < 4; ++j) {
      float vv[4] = {a4[j].x, a4[j].y, a4[j].z, a4[j].w};
      s16x4 h4, m4, l4;
#pragma unroll
      for (int e = 0; e < 4; ++e) {
        short hh = f2bf(vv[e]);
        float r1 = vv[e] - bf2f(hh);
        short mm = f2bf(r1);
        float r2 = r1 - bf2f(mm);
        h4[e] = hh; m4[e] = mm; l4[e] = f2bf(r2);
      }
      *(s16x4*)&Ah[arow][ak + 4*j] = h4;
      *(s16x4*)&Am[arow][ak + 4*j] = m4;
      *(s16x4*)&Al[arow][ak + 4*j] = l4;
    }
#pragma unroll
    for (int j = 0; j < 2; ++j) {
      float vv[4] = {b4[j].x, b4[j].y, b4[j].z, b4[j].w};
      s16x4 h4, m4, l4;
#pragma unroll
      for (int e = 0; e < 4; ++e) {
        short hh = f2bf(vv[e]);
        float r1 = vv[e] - bf2f(hh);
        short mm = f2bf(r1);
        float r2 = r1 - bf2f(mm);
        h4[e] = hh; m4[e] = mm; l4[e] = f2bf(r2);
      }
      *(s16x4*)&Bh[brow][bk + 4*j] = h4;
      *(s16x4*)&Bm[brow][bk + 4*j] = m4;
      *(s16x4*)&Bl[brow][bk + 4*j] = l4;
    }
    __syncthreads();

    bf16x8 ah[2], am[2], al[2];
#pragma unroll
    for (int ms = 0; ms < 2; ++ms) {
      int rr = wid*32 + ms*16 + bcol;
      ah[ms] = *(const bf16x8*)&Ah[rr][lgrp*8];
      am[ms] = *(const bf16x8*)&Am[rr][lgrp*8];
      al[ms] = *(const bf16x8*)&Al[rr][lgrp*8];
    }
#pragma unroll
    for (int nt = 0; nt < 4; ++nt) {
      int nr = nt*16 + bcol;
      bf16x8 bh = *(const bf16x8*)&Bh[nr][lgrp*8];
      bf16x8 bm = *(const bf16x8*)&Bm[nr][lgrp*8];
      bf16x8 bl = *(const bf16x8*)&Bl[nr][lgrp*8];
#pragma unroll
      for (int ms = 0; ms < 2; ++ms) {
        acch[ms][nt] = __builtin_amdgcn_mfma_f32_16x16x32_bf16(ah[ms], bh, acch[ms][nt], 0, 0, 0);
        accl[ms][nt] = __builtin_amdgcn_mfma_f32_16x16x32_bf16(ah[ms], bm, accl[ms][nt], 0, 0, 0);
        accl[ms][nt] = __builtin_amdgcn_mfma_f32_16x16x32_bf16(am[ms], bh, accl[ms][nt], 0, 0, 0);
        accl[ms][nt] = __builtin_amdgcn_mfma_f32_16x16x32_bf16(am[ms], bm, accl[ms][nt], 0, 0, 0);
        accl[ms][nt] = __builtin_amdgcn_mfma_f32_16x16x32_bf16(ah[ms], bl, accl[ms][nt], 0, 0, 0);
        accl[ms][nt] = __builtin_amdgcn_mfma_f32_16x16x32_bf16(al[ms], bh, accl[ms][nt], 0, 0, 0);
      }
    }
  }

#pragma unroll
  for (int ms = 0; ms < 2; ++ms)
#pragma unroll
    for (int nt = 0; nt < 4; ++nt)
#pragma unroll
      for (int rv = 0; rv < 4; ++rv) {
        int m = m0 + wid*32 + ms*16 + lgrp*4 + rv;
        int n = n0 + nt*16 + bcol;
        double val = (double)acch[ms][nt][rv] + (double)accl[ms][nt][rv] + (double)bias[n];
        int bb = m >> 11;
        int t = m & 2047;
        if (n < BNz) {
          int h = n >> 6, d = n & 63;
          q32[(((size_t)(bb*Hz + h))*Tz + t)*DHz + d] = (float)val;
        } else if (n < 2*BNz) {
          int h = (n - BNz) >> 6, d = n & 63;
          size_t bh = (size_t)(bb*Hz + h);
          float vf = (float)val;
          k32[(bh*Tz + t)*DHz + d] = vf;
          kbf[(bh*Tz + t)*DHz + d] = f2bf(vf);
        } else {
          int h = (n - 2*BNz) >> 6, d = n & 63;
          v32[(((size_t)(bb*Hz + h))*Tz + t)*DHz + d] = (float)val;
        }
      }
}

// ---- proj GEMM f32 (unchanged) --------------------------------------------
__global__ __launch_bounds__(256) void proj_gemm(
    const float* __restrict__ A, const float* __restrict__ W,
    const float* __restrict__ bias, float* __restrict__ out)
{
  __shared__ float As[16][68];
  __shared__ float Ws[16][68];
  const int tid = threadIdx.x;
  const int tx = tid & 15, ty = tid >> 4;
  const int m0 = blockIdx.y * 64, n0 = blockIdx.x * 64;
  const int lrow = tid >> 2, lkq = tid & 3;
  float acc[4][4] = {};
  const float* Aload = A + (size_t)(m0 + lrow) * Dz + lkq * 4;
  const float* Wload = W + (size_t)(n0 + lrow) * Dz + lkq * 4;
  for (int kt = 0; kt < Dz; kt += 16) {
    float4 a4 = *(const float4*)(Aload + kt);
    float4 w4 = *(const float4*)(Wload + kt);
    __syncthreads();
    As[lkq*4+0][lrow] = a4.x; As[lkq*4+1][lrow] = a4.y;
    As[lkq*4+2][lrow] = a4.z; As[lkq*4+3][lrow] = a4.w;
    Ws[lkq*4+0][lrow] = w4.x; Ws[lkq*4+1][lrow] = w4.y;
    Ws[lkq*4+2][lrow] = w4.z; Ws[lkq*4+3][lrow] = w4.w;
    __syncthreads();
#pragma unroll
    for (int k = 0; k < 16; ++k) {
      float4 av = *(const float4*)&As[k][ty*4];
      float4 wv = *(const float4*)&Ws[k][tx*4];
      float a_[4] = {av.x, av.y, av.z, av.w};
      float w_[4] = {wv.x, wv.y, wv.z, wv.w};
#pragma unroll
      for (int i = 0; i < 4; ++i)
#pragma unroll
        for (int j = 0; j < 4; ++j)
          acc[i][j] = fmaf(a_[i], w_[j], acc[i][j]);
    }
  }
#pragma unroll
  for (int i = 0; i < 4; ++i) {
    int m = m0 + ty*4 + i;
#pragma unroll
    for (int j = 0; j < 4; ++j) {
      int n = n0 + tx*4 + j;
      out[(size_t)m * Dz + n] = acc[i][j] + bias[n];
    }
  }
}

// ---- attention v10 = v9 with f32 q/k storage (f64 accumulate in rescore).
__global__ __launch_bounds__(256) void attn_topk(
    const float* __restrict__ q32g, const float* __restrict__ k32g,
    const short* __restrict__ kbfg, const float* __restrict__ v32,
    float* __restrict__ y)
{
  __shared__ float q_s[QBLK][DHz];                       // 4 KB
  __shared__ __align__(16) unsigned char ubuf[QBLK*CAND_MAX*6];
  __shared__ int bstar_s[QBLK];
  __shared__ int candcnt[QBLK];

  unsigned* hist = (unsigned*)ubuf;
  float* candv = (float*)ubuf;
  unsigned short* candidx = (unsigned short*)(ubuf + QBLK*CAND_MAX*4);

  const int tid = threadIdx.x;
  const int bid0 = blockIdx.x;
  const int bh_f = (bid0 & 7) + 8 * (bid0 >> 10);
  const int qbf = (bid0 >> 3) & 127;
  const int h = bh_f & 15;
  const int bb = bh_f >> 4;
  const size_t bh = (size_t)(bb * Hz + h);
  const float* qg = q32g + (bh * Tz + (size_t)qbf * QBLK) * DHz;
  const float* kg32 = k32g + bh * Tz * DHz;
  const short* kb = kbfg + bh * Tz * DHz;
  const float* vg = v32 + bh * Tz * DHz;

  if (tid < QBLK) candcnt[tid] = 0;
  for (int i = tid; i < QBLK*256; i += 256) hist[i] = 0u;
  {
    int r = tid >> 4, d4 = (tid & 15) * 4;
    *(float4*)&q_s[r][d4] = *(const float4*)&qg[r*DHz + d4];
  }
  __syncthreads();                                    // barrier 1

  const int lane = tid & 63;
  const int wid = tid >> 6;
  const int bcol = lane & 15;
  const int lgrp = lane >> 4;
  bf16x8 aF0, aF1;
#pragma unroll
  for (int e = 0; e < 8; ++e) {
    aF0[e] = f2bf(q_s[bcol][lgrp*8 + e]);
    aF1[e] = f2bf(q_s[bcol][32 + lgrp*8 + e]);
  }
  const int t0base = wid * 512;

  // ---- single MFMA pass: hist + pack bins into 32 registers ----
  unsigned binreg[32];
#pragma unroll 4
  for (int tt = 0; tt < 32; ++tt) {
    const short* kbp = kb + (size_t)(t0base + tt*16 + bcol) * DHz;
    bf16x8 b0 = *(const bf16x8*)(kbp + lgrp*8);
    bf16x8 b1 = *(const bf16x8*)(kbp + 32 + lgrp*8);
    f32x4 c = {0.f, 0.f, 0.f, 0.f};
    c = __builtin_amdgcn_mfma_f32_16x16x32_bf16(aF0, b0, c, 0, 0, 0);
    c = __builtin_amdgcn_mfma_f32_16x16x32_bf16(aF1, b1, c, 0, 0, 0);
    unsigned bw = 0u;
#pragma unroll
    for (int j = 0; j < 4; ++j) {
      int bin = (int)((c[j] - SLO) * SBINR);
      bin = bin < 0 ? 0 : (bin > 255 ? 255 : bin);
      atomicAdd(&hist[(lgrp*4 + j)*256 + bin], 1u);
      bw |= ((unsigned)bin) << (8*j);
    }
    binreg[tt] = bw;
  }
  __syncthreads();                                    // barrier 2

  // ---- parallel cut: 16-lane suffix scan + ballot -> crossing bin ----
  {
    int r = tid >> 4, i16 = tid & 15;
    int s = 0;
#pragma unroll
    for (int j = 0; j < 16; ++j) s += (int)hist[r*256 + i16*16 + j];
    int S = s;
#pragma unroll
    for (int off = 1; off < 16; off <<= 1) {
      int src = i16 + off;
      int v = __shfl(S, (lane & 48) | (src < 16 ? src : 15));
      S += (src < 16) ? v : 0;
    }
    unsigned long long blt = __ballot(S >= TOPKz);
    unsigned mask16 = (unsigned)((blt >> (lane & 48)) & 0xFFFFull);
    int istar = 31 - __builtin_clz(mask16);
    if (i16 == istar) {
      int cum = S - s;
      int b = istar * 16;
      for (int j = 15; j >= 0; --j) {
        cum += (int)hist[r*256 + istar*16 + j];
        if (cum >= TOPKz) { b = istar*16 + j; break; }
      }
      bstar_s[r] = b;
    }
  }
  __syncthreads();                                    // barrier 3 (hist dead)

  // ---- collect from REGISTERS: bin >= bstar-1 ----
  {
    int bc[4];
#pragma unroll
    for (int j = 0; j < 4; ++j) {
      int b = bstar_s[lgrp*4 + j] - 1;
      bc[j] = b < 0 ? 0 : b;
    }
#pragma unroll
    for (int tt = 0; tt < 32; ++tt) {
      unsigned bw = binreg[tt];
#pragma unroll
      for (int j = 0; j < 4; ++j) {
        int bin = (int)((bw >> (8*j)) & 255u);
        if (bin >= bc[j]) {
          int r = lgrp*4 + j;
          int p = atomicAdd(&candcnt[r], 1);
          if (p < CAND_MAX) candidx[r*CAND_MAX + p] = (unsigned short)(t0base + tt*16 + bcol);
        }
      }
    }
  }
  __syncthreads();                                    // barrier 4 (last)

  // ==== group-local: rescore (f32 loads, f64 accum) / rank / band / AV ====
  {
    const int r = tid >> 4, i16 = tid & 15;
    int n = candcnt[r]; if (n > CAND_MAX) n = CAND_MAX;

    for (int i = i16; i < n; i += 16) {
      int col = (int)candidx[r*CAND_MAX + i];
      const float* kpd = kg32 + (size_t)col * DHz;
      double s = 0.0;
#pragma unroll
      for (int d = 0; d < DHz; d += 4) {
        float4 k4 = *(const float4*)(kpd + d);
        s = fma((double)q_s[r][d+0], (double)k4.x, s);
        s = fma((double)q_s[r][d+1], (double)k4.y, s);
        s = fma((double)q_s[r][d+2], (double)k4.z, s);
        s = fma((double)q_s[r][d+3], (double)k4.w, s);
      }
      candv[r*CAND_MAX + i] = (float)s;
    }

    float myv[11];
    float mx = -3.0e38f;
#pragma unroll
    for (int j = 0; j < 11; ++j) {
      int i = i16 + j*16;
      float x = (i < n) ? candv[r*CAND_MAX + i] : -3.0e38f;
      myv[j] = x;
      mx = fmaxf(mx, x);
    }
#pragma unroll
    for (int m = 1; m < 16; m <<= 1) mx = fmaxf(mx, __shfl_xor(mx, m));

    float mn = 3.0e38f;
#pragma unroll
    for (int j = 0; j < 11; ++j) {
      int i = i16 + j*16;
      if (i < n) mn = fminf(mn, myv[j]);
    }
#pragma unroll
    for (int m = 1; m < 16; m <<= 1) mn = fminf(mn, __shfl_xor(mn, m));
    unsigned lo_u = f2s(mn);
    unsigned hi_u = f2s(mx) + 1u;
    while (hi_u - lo_u > 1u) {
      unsigned mid = lo_u + ((hi_u - lo_u) >> 1);
      float tv = s2f(mid);
      int cnt = 0;
#pragma unroll
      for (int j = 0; j < 11; ++j) cnt += (myv[j] >= tv) ? 1 : 0;
#pragma unroll
      for (int m = 1; m < 16; m <<= 1) cnt += __shfl_xor(cnt, m);
      if (cnt >= TOPKz) lo_u = mid; else hi_u = mid;
    }
    const float T = s2f(lo_u);

    int na = 0, nb = 0;
#pragma unroll
    for (int j = 0; j < 11; ++j) {
      float s = myv[j];
      if (s > T + BAND) na++;
      else if (s >= T - BAND) nb++;
    }
#pragma unroll
    for (int m = 1; m < 16; m <<= 1) {
      na += __shfl_xor(na, m);
      nb += __shfl_xor(nb, m);
    }
    const float wb = (float)(TOPKz - na) / (float)(nb > 0 ? nb : 1);

    float lsum = 0.f;
#pragma unroll
    for (int j = 0; j < 11; ++j) {
      int i = i16 + j*16;
      if (i < n) {
        float s = myv[j];
        float w = (s > T + BAND) ? 1.f : ((s >= T - BAND) ? wb : 0.f);
        float p = (w > 0.f) ? w * expf((s - mx) * 0.125f) : 0.f;
        candv[r*CAND_MAX + i] = p;
        lsum += p;
      }
    }
#pragma unroll
    for (int m = 1; m < 16; m <<= 1) lsum += __shfl_xor(lsum, m);
    const float rd = 1.0f / lsum;

    const int dg = i16 * 4;
    float4 o = make_float4(0.f, 0.f, 0.f, 0.f);
    for (int i = 0; i < n; ++i) {
      float p = candv[r*CAND_MAX + i];
      if (p > 0.f) {
        int idx = (int)candidx[r*CAND_MAX + i];
        float4 vv = *(const float4*)&vg[(size_t)idx*DHz + dg];
        float pw = p * rd;
        o.x = fmaf(pw, vv.x, o.x);
        o.y = fmaf(pw, vv.y, o.y);
        o.z = fmaf(pw, vv.z, o.z);
        o.w = fmaf(pw, vv.w, o.w);
      }
    }
    float* yo = y + ((size_t)bb*Tz + (size_t)qbf*QBLK + r) * BNz + h*DHz + dg;
    *(float4*)yo = o;
  }
}

extern "C" void kernel_launch(void* const* d_in, const int* in_sizes, int n_in,
                              void* d_out, int out_size, void* d_ws, size_t ws_size,
                              hipStream_t stream)
{
  const float* x      = (const float*)d_in[0];
  const float* w_qkv  = (const float*)d_in[1];
  const float* b_qkv  = (const float*)d_in[2];
  const float* w_proj = (const float*)d_in[3];
  const float* b_proj = (const float*)d_in[4];
  float* out = (float*)d_out;

  const size_t E = (size_t)Bz * Hz * Tz * DHz;   // 4,194,304
  float* q32  = (float*)d_ws;    // 16 MB
  float* k32  = q32 + E;         // 16 MB
  short* kbf  = (short*)(k32 + E);  // 8 MB
  float* v32  = (float*)(kbf + E);  // 16 MB
  float* y    = v32 + E;            // 16 MB (total 72 MB)

  qkv_gemm_split<<<dim3((3*BNz)/64, (Bz*Tz)/128), 256, 0, stream>>>(x, w_qkv, b_qkv, q32, k32, kbf, v32);
  attn_topk<<<Bz*Hz*(Tz/QBLK), 256, 0, stream>>>(q32, k32, kbf, v32, y);
  proj_gemm<<<dim3(Dz/64, (Bz*Tz)/64), 256, 0, stream>>>(y, w_proj, b_proj, out);
}

// Round 18
// 633.273 us; speedup vs baseline: 2.8961x; 1.1609x over previous
//
#include <hip/hip_runtime.h>
#include <hip/hip_bf16.h>
#include <math.h>

#define Bz 2
#define Tz 2048
#define Dz 1024
#define Hz 16
#define DHz 64
#define BNz 1024
#define TOPKz 64
#define QBLK 16
#define CAND_MAX 176
#define BAND 8e-5f    // ambiguity half-band on RAW scores (verified r5-r17)
#define SLO  -20.0f
#define SBINW 0.15625f
#define SBINR 6.4f
#define LDSB 40
#define HSTR 257      // hist row stride: 257%32==1 -> each row shifts banks by 1

typedef __attribute__((ext_vector_type(8))) short bf16x8;
typedef __attribute__((ext_vector_type(4))) short s16x4;
typedef __attribute__((ext_vector_type(4))) float f32x4;

__device__ __forceinline__ short f2bf(float f) {     // RNE f32 -> bf16
  unsigned u = __float_as_uint(f);
  return (short)((u + 0x7FFFu + ((u >> 16) & 1u)) >> 16);
}
__device__ __forceinline__ float bf2f(short b) {
  return __uint_as_float(((unsigned)(unsigned short)b) << 16);
}
__device__ __forceinline__ unsigned f2s(float f) {   // order-preserving f32->u32
  unsigned u = __float_as_uint(f);
  return (u & 0x80000000u) ? ~u : (u | 0x80000000u);
}
__device__ __forceinline__ float s2f(unsigned u) {
  return __uint_as_float((u & 0x80000000u) ? (u & 0x7FFFFFFFu) : ~u);
}

// ---- QKV GEMM via bf16x3 split (byte-identical to r17) --------------------
__global__ __launch_bounds__(256) void qkv_gemm_split(
    const float* __restrict__ A, const float* __restrict__ W,
    const float* __restrict__ bias,
    float* __restrict__ q32, float* __restrict__ k32,
    short* __restrict__ kbf, float* __restrict__ v32)
{
  __shared__ __align__(16) short Ah[128][LDSB];
  __shared__ __align__(16) short Am[128][LDSB];
  __shared__ __align__(16) short Al[128][LDSB];
  __shared__ __align__(16) short Bh[64][LDSB];
  __shared__ __align__(16) short Bm[64][LDSB];
  __shared__ __align__(16) short Bl[64][LDSB];

  const int tid = threadIdx.x;
  const int lane = tid & 63, wid = tid >> 6;
  const int m0 = blockIdx.y * 128, n0 = blockIdx.x * 64;
  const int bcol = lane & 15, lgrp = lane >> 4;

  f32x4 acch[2][4], accl[2][4];
#pragma unroll
  for (int ms = 0; ms < 2; ++ms)
#pragma unroll
    for (int nt = 0; nt < 4; ++nt) {
      acch[ms][nt] = (f32x4){0.f, 0.f, 0.f, 0.f};
      accl[ms][nt] = (f32x4){0.f, 0.f, 0.f, 0.f};
    }

  const int arow = tid >> 1, ak = (tid & 1) * 16;
  const int brow = tid >> 2, bk = (tid & 3) * 8;
  const float* Ald = A + (size_t)(m0 + arow) * Dz + ak;
  const float* Wld = W + (size_t)(n0 + brow) * Dz + bk;

  for (int kt = 0; kt < Dz; kt += 32) {
    float4 a4[4], b4[2];
#pragma unroll
    for (int j = 0; j < 4; ++j) a4[j] = *(const float4*)(Ald + kt + 4*j);
#pragma unroll
    for (int j = 0; j < 2; ++j) b4[j] = *(const float4*)(Wld + kt + 4*j);
    __syncthreads();

#pragma unroll
    for (int j = 0; j < 4; ++j) {
      float vv[4] = {a4[j].x, a4[j].y, a4[j].z, a4[j].w};
      s16x4 h4, m4, l4;
#pragma unroll
      for (int e = 0; e < 4; ++e) {
        short hh = f2bf(vv[e]);
        float r1 = vv[e] - bf2f(hh);
        short mm = f2bf(r1);
        float r2 = r1 - bf2f(mm);
        h4[e] = hh; m4[e] = mm; l4[e] = f2bf(r2);
      }
      *(s16x4*)&Ah[arow][ak + 4*j] = h4;
      *(s16x4*)&Am[arow][ak + 4*j] = m4;
      *(s16x4*)&Al[arow][ak + 4*j] = l4;
    }
#pragma unroll
    for (int j = 0; j < 2; ++j) {
      float vv[4] = {b4[j].x, b4[j].y, b4[j].z, b4[j].w};
      s16x4 h4, m4, l4;
#pragma unroll
      for (int e = 0; e < 4; ++e) {
        short hh = f2bf(vv[e]);
        float r1 = vv[e] - bf2f(hh);
        short mm = f2bf(r1);
        float r2 = r1 - bf2f(mm);
        h4[e] = hh; m4[e] = mm; l4[e] = f2bf(r2);
      }
      *(s16x4*)&Bh[brow][bk + 4*j] = h4;
      *(s16x4*)&Bm[brow][bk + 4*j] = m4;
      *(s16x4*)&Bl[brow][bk + 4*j] = l4;
    }
    __syncthreads();

    bf16x8 ah[2], am[2], al[2];
#pragma unroll
    for (int ms = 0; ms < 2; ++ms) {
      int rr = wid*32 + ms*16 + bcol;
      ah[ms] = *(const bf16x8*)&Ah[rr][lgrp*8];
      am[ms] = *(const bf16x8*)&Am[rr][lgrp*8];
      al[ms] = *(const bf16x8*)&Al[rr][lgrp*8];
    }
#pragma unroll
    for (int nt = 0; nt < 4; ++nt) {
      int nr = nt*16 + bcol;
      bf16x8 bh = *(const bf16x8*)&Bh[nr][lgrp*8];
      bf16x8 bm = *(const bf16x8*)&Bm[nr][lgrp*8];
      bf16x8 bl = *(const bf16x8*)&Bl[nr][lgrp*8];
#pragma unroll
      for (int ms = 0; ms < 2; ++ms) {
        acch[ms][nt] = __builtin_amdgcn_mfma_f32_16x16x32_bf16(ah[ms], bh, acch[ms][nt], 0, 0, 0);
        accl[ms][nt] = __builtin_amdgcn_mfma_f32_16x16x32_bf16(ah[ms], bm, accl[ms][nt], 0, 0, 0);
        accl[ms][nt] = __builtin_amdgcn_mfma_f32_16x16x32_bf16(am[ms], bh, accl[ms][nt], 0, 0, 0);
        accl[ms][nt] = __builtin_amdgcn_mfma_f32_16x16x32_bf16(am[ms], bm, accl[ms][nt], 0, 0, 0);
        accl[ms][nt] = __builtin_amdgcn_mfma_f32_16x16x32_bf16(ah[ms], bl, accl[ms][nt], 0, 0, 0);
        accl[ms][nt] = __builtin_amdgcn_mfma_f32_16x16x32_bf16(al[ms], bh, accl[ms][nt], 0, 0, 0);
      }
    }
  }

#pragma unroll
  for (int ms = 0; ms < 2; ++ms)
#pragma unroll
    for (int nt = 0; nt < 4; ++nt)
#pragma unroll
      for (int rv = 0; rv < 4; ++rv) {
        int m = m0 + wid*32 + ms*16 + lgrp*4 + rv;
        int n = n0 + nt*16 + bcol;
        double val = (double)acch[ms][nt][rv] + (double)accl[ms][nt][rv] + (double)bias[n];
        int bb = m >> 11;
        int t = m & 2047;
        if (n < BNz) {
          int h = n >> 6, d = n & 63;
          q32[(((size_t)(bb*Hz + h))*Tz + t)*DHz + d] = (float)val;
        } else if (n < 2*BNz) {
          int h = (n - BNz) >> 6, d = n & 63;
          size_t bh = (size_t)(bb*Hz + h);
          float vf = (float)val;
          k32[(bh*Tz + t)*DHz + d] = vf;
          kbf[(bh*Tz + t)*DHz + d] = f2bf(vf);
        } else {
          int h = (n - 2*BNz) >> 6, d = n & 63;
          v32[(((size_t)(bb*Hz + h))*Tz + t)*DHz + d] = (float)val;
        }
      }
}

// ---- proj GEMM via bf16x3 split MFMA (same verified machinery) ------------
__global__ __launch_bounds__(256) void proj_gemm_split(
    const float* __restrict__ A, const float* __restrict__ W,
    const float* __restrict__ bias, float* __restrict__ out)
{
  __shared__ __align__(16) short Ah[128][LDSB];
  __shared__ __align__(16) short Am[128][LDSB];
  __shared__ __align__(16) short Al[128][LDSB];
  __shared__ __align__(16) short Bh[64][LDSB];
  __shared__ __align__(16) short Bm[64][LDSB];
  __shared__ __align__(16) short Bl[64][LDSB];

  const int tid = threadIdx.x;
  const int lane = tid & 63, wid = tid >> 6;
  const int m0 = blockIdx.y * 128, n0 = blockIdx.x * 64;
  const int bcol = lane & 15, lgrp = lane >> 4;

  f32x4 acch[2][4], accl[2][4];
#pragma unroll
  for (int ms = 0; ms < 2; ++ms)
#pragma unroll
    for (int nt = 0; nt < 4; ++nt) {
      acch[ms][nt] = (f32x4){0.f, 0.f, 0.f, 0.f};
      accl[ms][nt] = (f32x4){0.f, 0.f, 0.f, 0.f};
    }

  const int arow = tid >> 1, ak = (tid & 1) * 16;
  const int brow = tid >> 2, bk = (tid & 3) * 8;
  const float* Ald = A + (size_t)(m0 + arow) * Dz + ak;
  const float* Wld = W + (size_t)(n0 + brow) * Dz + bk;

  for (int kt = 0; kt < Dz; kt += 32) {
    float4 a4[4], b4[2];
#pragma unroll
    for (int j = 0; j < 4; ++j) a4[j] = *(const float4*)(Ald + kt + 4*j);
#pragma unroll
    for (int j = 0; j < 2; ++j) b4[j] = *(const float4*)(Wld + kt + 4*j);
    __syncthreads();

#pragma unroll
    for (int j = 0; j < 4; ++j) {
      float vv[4] = {a4[j].x, a4[j].y, a4[j].z, a4[j].w};
      s16x4 h4, m4, l4;
#pragma unroll
      for (int e = 0; e < 4; ++e) {
        short hh = f2bf(vv[e]);
        float r1 = vv[e] - bf2f(hh);
        short mm = f2bf(r1);
        float r2 = r1 - bf2f(mm);
        h4[e] = hh; m4[e] = mm; l4[e] = f2bf(r2);
      }
      *(s16x4*)&Ah[arow][ak + 4*j] = h4;
      *(s16x4*)&Am[arow][ak + 4*j] = m4;
      *(s16x4*)&Al[arow][ak + 4*j] = l4;
    }
#pragma unroll
    for (int j = 0; j < 2; ++j) {
      float vv[4] = {b4[j].x, b4[j].y, b4[j].z, b4[j].w};
      s16x4 h4, m4, l4;
#pragma unroll
      for (int e = 0; e < 4; ++e) {
        short hh = f2bf(vv[e]);
        float r1 = vv[e] - bf2f(hh);
        short mm = f2bf(r1);
        float r2 = r1 - bf2f(mm);
        h4[e] = hh; m4[e] = mm; l4[e] = f2bf(r2);
      }
      *(s16x4*)&Bh[brow][bk + 4*j] = h4;
      *(s16x4*)&Bm[brow][bk + 4*j] = m4;
      *(s16x4*)&Bl[brow][bk + 4*j] = l4;
    }
    __syncthreads();

    bf16x8 ah[2], am[2], al[2];
#pragma unroll
    for (int ms = 0; ms < 2; ++ms) {
      int rr = wid*32 + ms*16 + bcol;
      ah[ms] = *(const bf16x8*)&Ah[rr][lgrp*8];
      am[ms] = *(const bf16x8*)&Am[rr][lgrp*8];
      al[ms] = *(const bf16x8*)&Al[rr][lgrp*8];
    }
#pragma unroll
    for (int nt = 0; nt < 4; ++nt) {
      int nr = nt*16 + bcol;
      bf16x8 bh = *(const bf16x8*)&Bh[nr][lgrp*8];
      bf16x8 bm = *(const bf16x8*)&Bm[nr][lgrp*8];
      bf16x8 bl = *(const bf16x8*)&Bl[nr][lgrp*8];
#pragma unroll
      for (int ms = 0; ms < 2; ++ms) {
        acch[ms][nt] = __builtin_amdgcn_mfma_f32_16x16x32_bf16(ah[ms], bh, acch[ms][nt], 0, 0, 0);
        accl[ms][nt] = __builtin_amdgcn_mfma_f32_16x16x32_bf16(ah[ms], bm, accl[ms][nt], 0, 0, 0);
        accl[ms][nt] = __builtin_amdgcn_mfma_f32_16x16x32_bf16(am[ms], bh, accl[ms][nt], 0, 0, 0);
        accl[ms][nt] = __builtin_amdgcn_mfma_f32_16x16x32_bf16(am[ms], bm, accl[ms][nt], 0, 0, 0);
        accl[ms][nt] = __builtin_amdgcn_mfma_f32_16x16x32_bf16(ah[ms], bl, accl[ms][nt], 0, 0, 0);
        accl[ms][nt] = __builtin_amdgcn_mfma_f32_16x16x32_bf16(al[ms], bh, accl[ms][nt], 0, 0, 0);
      }
    }
  }

#pragma unroll
  for (int ms = 0; ms < 2; ++ms)
#pragma unroll
    for (int nt = 0; nt < 4; ++nt)
#pragma unroll
      for (int rv = 0; rv < 4; ++rv) {
        int m = m0 + wid*32 + ms*16 + lgrp*4 + rv;
        int n = n0 + nt*16 + bcol;
        out[(size_t)m * Dz + n] = (acch[ms][nt][rv] + accl[ms][nt][rv]) + bias[n];
      }
}

// ---- attention v11 = v10 + bank-spread histogram (stride 257) + branchless AV
__global__ __launch_bounds__(256) void attn_topk(
    const float* __restrict__ q32g, const float* __restrict__ k32g,
    const short* __restrict__ kbfg, const float* __restrict__ v32,
    float* __restrict__ y)
{
  __shared__ float q_s[QBLK][DHz];
  __shared__ __align__(16) unsigned char ubuf[QBLK*CAND_MAX*6];  // 16896 B >= 16*257*4=16448
  __shared__ int bstar_s[QBLK];
  __shared__ int candcnt[QBLK];

  unsigned* hist = (unsigned*)ubuf;                   // [16][HSTR]
  float* candv = (float*)ubuf;                        // [16][CAND_MAX]
  unsigned short* candidx = (unsigned short*)(ubuf + QBLK*CAND_MAX*4);

  const int tid = threadIdx.x;
  const int bid0 = blockIdx.x;
  const int bh_f = (bid0 & 7) + 8 * (bid0 >> 10);
  const int qbf = (bid0 >> 3) & 127;
  const int h = bh_f & 15;
  const int bb = bh_f >> 4;
  const size_t bh = (size_t)(bb * Hz + h);
  const float* qg = q32g + (bh * Tz + (size_t)qbf * QBLK) * DHz;
  const float* kg32 = k32g + bh * Tz * DHz;
  const short* kb = kbfg + bh * Tz * DHz;
  const float* vg = v32 + bh * Tz * DHz;

  if (tid < QBLK) candcnt[tid] = 0;
  for (int i = tid; i < QBLK*HSTR; i += 256) hist[i] = 0u;
  {
    int r = tid >> 4, d4 = (tid & 15) * 4;
    *(float4*)&q_s[r][d4] = *(const float4*)&qg[r*DHz + d4];
  }
  __syncthreads();                                    // barrier 1

  const int lane = tid & 63;
  const int wid = tid >> 6;
  const int bcol = lane & 15;
  const int lgrp = lane >> 4;
  bf16x8 aF0, aF1;
#pragma unroll
  for (int e = 0; e < 8; ++e) {
    aF0[e] = f2bf(q_s[bcol][lgrp*8 + e]);
    aF1[e] = f2bf(q_s[bcol][32 + lgrp*8 + e]);
  }
  const int t0base = wid * 512;

  // ---- single MFMA pass: hist + pack bins into 32 registers ----
  unsigned binreg[32];
#pragma unroll 4
  for (int tt = 0; tt < 32; ++tt) {
    const short* kbp = kb + (size_t)(t0base + tt*16 + bcol) * DHz;
    bf16x8 b0 = *(const bf16x8*)(kbp + lgrp*8);
    bf16x8 b1 = *(const bf16x8*)(kbp + 32 + lgrp*8);
    f32x4 c = {0.f, 0.f, 0.f, 0.f};
    c = __builtin_amdgcn_mfma_f32_16x16x32_bf16(aF0, b0, c, 0, 0, 0);
    c = __builtin_amdgcn_mfma_f32_16x16x32_bf16(aF1, b1, c, 0, 0, 0);
    unsigned bw = 0u;
#pragma unroll
    for (int j = 0; j < 4; ++j) {
      int bin = (int)((c[j] - SLO) * SBINR);
      bin = bin < 0 ? 0 : (bin > 255 ? 255 : bin);
      atomicAdd(&hist[(lgrp*4 + j)*HSTR + bin], 1u);
      bw |= ((unsigned)bin) << (8*j);
    }
    binreg[tt] = bw;
  }
  __syncthreads();                                    // barrier 2

  // ---- parallel cut: 16-lane suffix scan + ballot -> crossing bin ----
  {
    int r = tid >> 4, i16 = tid & 15;
    int s = 0;
#pragma unroll
    for (int j = 0; j < 16; ++j) s += (int)hist[r*HSTR + i16*16 + j];
    int S = s;
#pragma unroll
    for (int off = 1; off < 16; off <<= 1) {
      int src = i16 + off;
      int v = __shfl(S, (lane & 48) | (src < 16 ? src : 15));
      S += (src < 16) ? v : 0;
    }
    unsigned long long blt = __ballot(S >= TOPKz);
    unsigned mask16 = (unsigned)((blt >> (lane & 48)) & 0xFFFFull);
    int istar = 31 - __builtin_clz(mask16);
    if (i16 == istar) {
      int cum = S - s;
      int b = istar * 16;
      for (int j = 15; j >= 0; --j) {
        cum += (int)hist[r*HSTR + istar*16 + j];
        if (cum >= TOPKz) { b = istar*16 + j; break; }
      }
      bstar_s[r] = b;
    }
  }
  __syncthreads();                                    // barrier 3 (hist dead)

  // ---- collect from REGISTERS: bin >= bstar-1 ----
  {
    int bc[4];
#pragma unroll
    for (int j = 0; j < 4; ++j) {
      int b = bstar_s[lgrp*4 + j] - 1;
      bc[j] = b < 0 ? 0 : b;
    }
#pragma unroll
    for (int tt = 0; tt < 32; ++tt) {
      unsigned bw = binreg[tt];
#pragma unroll
      for (int j = 0; j < 4; ++j) {
        int bin = (int)((bw >> (8*j)) & 255u);
        if (bin >= bc[j]) {
          int r = lgrp*4 + j;
          int p = atomicAdd(&candcnt[r], 1);
          if (p < CAND_MAX) candidx[r*CAND_MAX + p] = (unsigned short)(t0base + tt*16 + bcol);
        }
      }
    }
  }
  __syncthreads();                                    // barrier 4 (last)

  // ==== group-local: rescore (f32 loads, f64 accum) / rank / band / AV ====
  {
    const int r = tid >> 4, i16 = tid & 15;
    int n = candcnt[r]; if (n > CAND_MAX) n = CAND_MAX;

    for (int i = i16; i < n; i += 16) {
      int col = (int)candidx[r*CAND_MAX + i];
      const float* kpd = kg32 + (size_t)col * DHz;
      double s = 0.0;
#pragma unroll
      for (int d = 0; d < DHz; d += 4) {
        float4 k4 = *(const float4*)(kpd + d);
        s = fma((double)q_s[r][d+0], (double)k4.x, s);
        s = fma((double)q_s[r][d+1], (double)k4.y, s);
        s = fma((double)q_s[r][d+2], (double)k4.z, s);
        s = fma((double)q_s[r][d+3], (double)k4.w, s);
      }
      candv[r*CAND_MAX + i] = (float)s;
    }

    float myv[11];
    float mx = -3.0e38f;
#pragma unroll
    for (int j = 0; j < 11; ++j) {
      int i = i16 + j*16;
      float x = (i < n) ? candv[r*CAND_MAX + i] : -3.0e38f;
      myv[j] = x;
      mx = fmaxf(mx, x);
    }
#pragma unroll
    for (int m = 1; m < 16; m <<= 1) mx = fmaxf(mx, __shfl_xor(mx, m));

    float mn = 3.0e38f;
#pragma unroll
    for (int j = 0; j < 11; ++j) {
      int i = i16 + j*16;
      if (i < n) mn = fminf(mn, myv[j]);
    }
#pragma unroll
    for (int m = 1; m < 16; m <<= 1) mn = fminf(mn, __shfl_xor(mn, m));
    unsigned lo_u = f2s(mn);
    unsigned hi_u = f2s(mx) + 1u;
    while (hi_u - lo_u > 1u) {
      unsigned mid = lo_u + ((hi_u - lo_u) >> 1);
      float tv = s2f(mid);
      int cnt = 0;
#pragma unroll
      for (int j = 0; j < 11; ++j) cnt += (myv[j] >= tv) ? 1 : 0;
#pragma unroll
      for (int m = 1; m < 16; m <<= 1) cnt += __shfl_xor(cnt, m);
      if (cnt >= TOPKz) lo_u = mid; else hi_u = mid;
    }
    const float T = s2f(lo_u);

    int na = 0, nb = 0;
#pragma unroll
    for (int j = 0; j < 11; ++j) {
      float s = myv[j];
      if (s > T + BAND) na++;
      else if (s >= T - BAND) nb++;
    }
#pragma unroll
    for (int m = 1; m < 16; m <<= 1) {
      na += __shfl_xor(na, m);
      nb += __shfl_xor(nb, m);
    }
    const float wb = (float)(TOPKz - na) / (float)(nb > 0 ? nb : 1);

    float lsum = 0.f;
#pragma unroll
    for (int j = 0; j < 11; ++j) {
      int i = i16 + j*16;
      if (i < n) {
        float s = myv[j];
        float w = (s > T + BAND) ? 1.f : ((s >= T - BAND) ? wb : 0.f);
        float p = (w > 0.f) ? w * expf((s - mx) * 0.125f) : 0.f;
        candv[r*CAND_MAX + i] = p;
        lsum += p;
      }
    }
#pragma unroll
    for (int m = 1; m < 16; m <<= 1) lsum += __shfl_xor(lsum, m);
    const float rd = 1.0f / lsum;

    // branchless AV: p==0 terms contribute 0; removing the guard lets the
    // compiler pipeline the 16B V loads across iterations.
    const int dg = i16 * 4;
    float4 o = make_float4(0.f, 0.f, 0.f, 0.f);
    for (int i = 0; i < n; ++i) {
      float p = candv[r*CAND_MAX + i];
      int idx = (int)candidx[r*CAND_MAX + i];
      float4 vv = *(const float4*)&vg[(size_t)idx*DHz + dg];
      float pw = p * rd;
      o.x = fmaf(pw, vv.x, o.x);
      o.y = fmaf(pw, vv.y, o.y);
      o.z = fmaf(pw, vv.z, o.z);
      o.w = fmaf(pw, vv.w, o.w);
    }
    float* yo = y + ((size_t)bb*Tz + (size_t)qbf*QBLK + r) * BNz + h*DHz + dg;
    *(float4*)yo = o;
  }
}

extern "C" void kernel_launch(void* const* d_in, const int* in_sizes, int n_in,
                              void* d_out, int out_size, void* d_ws, size_t ws_size,
                              hipStream_t stream)
{
  const float* x      = (const float*)d_in[0];
  const float* w_qkv  = (const float*)d_in[1];
  const float* b_qkv  = (const float*)d_in[2];
  const float* w_proj = (const float*)d_in[3];
  const float* b_proj = (const float*)d_in[4];
  float* out = (float*)d_out;

  const size_t E = (size_t)Bz * Hz * Tz * DHz;   // 4,194,304
  float* q32  = (float*)d_ws;       // 16 MB
  float* k32  = q32 + E;            // 16 MB
  short* kbf  = (short*)(k32 + E);  // 8 MB
  float* v32  = (float*)(kbf + E);  // 16 MB
  float* y    = v32 + E;            // 16 MB (total 72 MB)

  qkv_gemm_split<<<dim3((3*BNz)/64, (Bz*Tz)/128), 256, 0, stream>>>(x, w_qkv, b_qkv, q32, k32, kbf, v32);
  attn_topk<<<Bz*Hz*(Tz/QBLK), 256, 0, stream>>>(q32, k32, kbf, v32, y);
  proj_gemm_split<<<dim3(Dz/64, (Bz*Tz)/128), 256, 0, stream>>>(y, w_proj, b_proj, out);
}